// Round 14
// baseline (562.452 us; speedup 1.0000x reference)
//
#include <hip/hip_runtime.h>
#include <hip/hip_bf16.h>
#include <hip/hip_cooperative_groups.h>

namespace cg = cooperative_groups;

// ---------------------------------------------------------------------------
// GAT encoder, 2 layers. Round 14: round-13 structure +
//  - single cooperative front-end kernel (zero+wprep | rank+xprep | scan |
//    scan_write | place) -> 5 dispatches total
//  - node gather with 8-lane groups (16 row loads in flight per wave)
// ---------------------------------------------------------------------------

#define NEG_SLOPE 0.2f
#define SCAN_SEG 2048
#define NREP 4
#define CSR_BLOCKS 832   // 832*256*4 >= E+N = 850000

typedef __attribute__((ext_vector_type(8))) short bf16x8;
typedef __attribute__((ext_vector_type(4))) float f32x4;

__device__ __forceinline__ unsigned short f2bf(float v) {
    __hip_bfloat16 b = __float2bfloat16(v);
    return *reinterpret_cast<unsigned short*>(&b);
}
__device__ __forceinline__ float bf2f(unsigned short u) {
    __hip_bfloat16 b = *reinterpret_cast<__hip_bfloat16*>(&u);
    return __bfloat162float(b);
}

// ---------------------------------------------------------------------------
// Cooperative front-end: all CSR + prep work in one launch.
// phase0: zero cnt; W1/W2 transpose->bf16; w_s1/w_d1 = W1 @ a_{src,dst}1
// phase1: rank (4-replica counters, VPT=4) ; xprep (x->bf16, s/d dots)
// phase2: per-segment count sums -> part[]
// phase3: scan_write (rowptr + absolute replica bases; in-block part prefix)
// phase4: place (atomic-free CSR fill)
// ---------------------------------------------------------------------------
__global__ __launch_bounds__(256) void fused_pre_k(
    const int* __restrict__ srcE, const int* __restrict__ dstE,
    const float* __restrict__ x, const float* __restrict__ W1,
    const float* __restrict__ W2, const float* __restrict__ a_src1,
    const float* __restrict__ a_dst1, int* __restrict__ cnt,
    int* __restrict__ rank, int* __restrict__ rowptr, int* __restrict__ part,
    int* __restrict__ ssrc, unsigned short* __restrict__ xbf,
    unsigned short* __restrict__ w1T, unsigned short* __restrict__ w2T,
    float* __restrict__ w_s1, float* __restrict__ w_d1,
    float* __restrict__ sbuf, float* __restrict__ dbuf, int E, int N) {
    cg::grid_group grid = cg::this_grid();
    const int tid = threadIdx.x;
    const int gtid = blockIdx.x * 256 + tid;
    const int nth = gridDim.x * 256;
    const int total = E + N;
    const int nseg = (N + SCAN_SEG - 1) / SCAN_SEG;
    __shared__ int wsum[4];
    __shared__ int pbase_s, ptot_s;

    // ---- phase 0 ----
    for (int i = gtid; i < NREP * N; i += nth) cnt[i] = 0;
    if (blockIdx.x < 128) {                    // W1[128][256] -> w1T[256][128]
        int i = blockIdx.x * 256 + tid;
        int k = i >> 8, n = i & 255;
        w1T[n * 128 + k] = f2bf(W1[i]);
    } else if (blockIdx.x < 256) {             // W2[256][128] -> w2T[128][256]
        int j = (blockIdx.x - 128) * 256 + tid;
        int k = j >> 7, n = j & 127;
        w2T[n * 256 + k] = f2bf(W2[j]);
    } else if (blockIdx.x < 288) {             // projection dots
        int w = ((blockIdx.x - 256) * 256 + tid) >> 6;  // 0..127
        int lane = tid & 63;
        const float* row = W1 + (size_t)w * 256;
        float ss = 0.f, dd = 0.f;
        #pragma unroll
        for (int f = lane; f < 256; f += 64) {
            float v = row[f];
            ss += v * a_src1[f];
            dd += v * a_dst1[f];
        }
        #pragma unroll
        for (int off = 32; off; off >>= 1) {
            ss += __shfl_down(ss, off);
            dd += __shfl_down(dd, off);
        }
        if (lane == 0) { w_s1[w] = ss; w_d1[w] = dd; }
    }
    grid.sync();

    // ---- phase 1: rank + xprep ----
    {
        const int rep = tid & (NREP - 1);
        int idx[4], di[4], r[4];
        #pragma unroll
        for (int k = 0; k < 4; ++k) {
            idx[k] = gtid + k * nth;
            if (idx[k] < total)
                di[k] = (idx[k] < E) ? dstE[idx[k]] : idx[k] - E;
        }
        #pragma unroll
        for (int k = 0; k < 4; ++k)
            if (idx[k] < total) r[k] = atomicAdd(&cnt[rep * N + di[k]], 1);
        #pragma unroll
        for (int k = 0; k < 4; ++k)
            if (idx[k] < total) rank[idx[k]] = (r[k] << 2) | rep;
    }
    {
        const int gw = gtid >> 6;
        const int nw = nth >> 6;
        const int lane = tid & 63;
        for (int w = gw; w < N; w += nw) {
            float2 v = *(const float2*)(x + (size_t)w * 128 + lane * 2);
            ushort2 u;
            u.x = f2bf(v.x);
            u.y = f2bf(v.y);
            *(ushort2*)(xbf + (size_t)w * 128 + lane * 2) = u;
            float ss = v.x * w_s1[lane * 2] + v.y * w_s1[lane * 2 + 1];
            float dd = v.x * w_d1[lane * 2] + v.y * w_d1[lane * 2 + 1];
            #pragma unroll
            for (int off = 32; off; off >>= 1) {
                ss += __shfl_down(ss, off);
                dd += __shfl_down(dd, off);
            }
            if (lane == 0) { sbuf[w] = ss; dbuf[w] = dd; }
        }
    }
    grid.sync();

    // ---- phase 2: per-segment sums ----
    if (blockIdx.x < nseg) {
        const int base = blockIdx.x * SCAN_SEG;
        const int lim = min(base + SCAN_SEG, N);
        int s = 0;
        for (int i = base + tid; i < lim; i += 256)
            s += cnt[i] + cnt[N + i] + cnt[2 * N + i] + cnt[3 * N + i];
        #pragma unroll
        for (int off = 32; off; off >>= 1) s += __shfl_down(s, off);
        if ((tid & 63) == 0) wsum[tid >> 6] = s;
        __syncthreads();
        if (tid == 0) part[blockIdx.x] = wsum[0] + wsum[1] + wsum[2] + wsum[3];
    }
    grid.sync();

    // ---- phase 3: scan_write (+ in-block part prefix) ----
    if (blockIdx.x < nseg) {
        if (tid < 64) {
            int v = (tid < nseg) ? part[tid] : 0;
            int incl = v;
            #pragma unroll
            for (int off = 1; off < 64; off <<= 1) {
                int t = __shfl_up(incl, off);
                if ((tid & 63) >= off) incl += t;
            }
            if (tid == (int)blockIdx.x) pbase_s = incl - v;
            if (tid == 63) ptot_s = incl;
        }
        __syncthreads();
        const int lane = tid & 63;
        const int wv = tid >> 6;
        const int tbase = blockIdx.x * SCAN_SEG + tid * 8;
        int local[8];
        int s = 0;
        #pragma unroll
        for (int q = 0; q < 8; ++q) {
            int idx = tbase + q;
            int tot = 0;
            if (idx < N)
                tot = cnt[idx] + cnt[N + idx] + cnt[2 * N + idx] + cnt[3 * N + idx];
            local[q] = s;
            s += tot;
        }
        int incl = s;
        #pragma unroll
        for (int off = 1; off < 64; off <<= 1) {
            int t = __shfl_up(incl, off);
            if (lane >= off) incl += t;
        }
        if (lane == 63) wsum[wv] = incl;
        __syncthreads();
        if (tid == 0) {
            int r = 0;
            #pragma unroll
            for (int i = 0; i < 4; ++i) { int c = wsum[i]; wsum[i] = r; r += c; }
        }
        __syncthreads();
        const int base = pbase_s + wsum[wv] + (incl - s);
        #pragma unroll
        for (int q = 0; q < 8; ++q) {
            int idx = tbase + q;
            if (idx < N) {
                int pos = base + local[q];
                rowptr[idx] = pos;
                int c0 = cnt[idx], c1 = cnt[N + idx], c2 = cnt[2 * N + idx];
                cnt[idx] = pos;
                cnt[N + idx] = pos + c0;
                cnt[2 * N + idx] = pos + c0 + c1;
                cnt[3 * N + idx] = pos + c0 + c1 + c2;
            }
        }
        if (blockIdx.x == 0 && tid == 0) rowptr[N] = ptot_s;
    }
    grid.sync();

    // ---- phase 4: place ----
    {
        int idx[4], si[4], di[4], pk[4];
        #pragma unroll
        for (int k = 0; k < 4; ++k) {
            idx[k] = gtid + k * nth;
            if (idx[k] < total) {
                if (idx[k] < E) { si[k] = srcE[idx[k]]; di[k] = dstE[idx[k]]; }
                else            { si[k] = di[k] = idx[k] - E; }
                pk[k] = rank[idx[k]];
            }
        }
        int pos[4];
        #pragma unroll
        for (int k = 0; k < 4; ++k)
            if (idx[k] < total) pos[k] = cnt[(pk[k] & 3) * N + di[k]];
        #pragma unroll
        for (int k = 0; k < 4; ++k)
            if (idx[k] < total) ssrc[pos[k] + (pk[k] >> 2)] = si[k];
    }
}

// ---- bf16 MFMA GEMM, BM=128 BN=128 BK=32, 4 waves (32 rows x 128 cols each).
// EPI=1: relu(acc+bias[col]) -> bf16 C. EPI=2: bf16 C + in-register rowdots.
template <int K, int NN, int EPI>
__global__ __launch_bounds__(256) void gemm_bf16(
    const unsigned short* __restrict__ A, const unsigned short* __restrict__ BT,
    unsigned short* __restrict__ C, const float* __restrict__ bias,
    const float* __restrict__ va, const float* __restrict__ vb,
    float* __restrict__ sOut, float* __restrict__ dOut, int M) {
    constexpr int BK = 32, PAD = 8;
    __shared__ short As[128][BK + PAD];
    __shared__ short Bs[128][BK + PAD];
    const int tid = threadIdx.x;
    const int wv = tid >> 6;
    const int ln = tid & 63;
    const int row0 = blockIdx.x * 128;
    const int col0 = blockIdx.y * 128;

    f32x4 acc[2][8];
    #pragma unroll
    for (int m = 0; m < 2; ++m)
        #pragma unroll
        for (int n = 0; n < 8; ++n) acc[m][n] = {0.f, 0.f, 0.f, 0.f};

    const int l15 = ln & 15;
    const int kg = (ln >> 4) * 8;

    for (int k0 = 0; k0 < K; k0 += BK) {
        #pragma unroll
        for (int t = 0; t < 2; ++t) {
            int v = tid + t * 256;
            int r = v >> 2;
            int kc = (v & 3) * 8;
            bf16x8 val = {0, 0, 0, 0, 0, 0, 0, 0};
            int gr = row0 + r;
            if (gr < M)
                val = *(const bf16x8*)(A + (size_t)gr * K + k0 + kc);
            *(bf16x8*)(&As[r][kc]) = val;
        }
        #pragma unroll
        for (int t = 0; t < 2; ++t) {
            int v = tid + t * 256;
            int c = v >> 2;
            int kc = (v & 3) * 8;
            *(bf16x8*)(&Bs[c][kc]) =
                *(const bf16x8*)(BT + (size_t)(col0 + c) * K + k0 + kc);
        }
        __syncthreads();

        bf16x8 ah[2], bh[8];
        #pragma unroll
        for (int m = 0; m < 2; ++m)
            ah[m] = *(const bf16x8*)&As[wv * 32 + m * 16 + l15][kg];
        #pragma unroll
        for (int n = 0; n < 8; ++n)
            bh[n] = *(const bf16x8*)&Bs[n * 16 + l15][kg];
        #pragma unroll
        for (int m = 0; m < 2; ++m)
            #pragma unroll
            for (int n = 0; n < 8; ++n)
                acc[m][n] = __builtin_amdgcn_mfma_f32_16x16x32_bf16(
                    ah[m], bh[n], acc[m][n], 0, 0, 0);
        __syncthreads();
    }

    // C/D layout: col=lane&15, row=(lane>>4)*4+reg
    const int crow = (ln >> 4) * 4;
    #pragma unroll
    for (int m = 0; m < 2; ++m) {
        #pragma unroll
        for (int q = 0; q < 4; ++q) {
            int gr = row0 + wv * 32 + m * 16 + crow + q;
            if (gr >= M) continue;
            if constexpr (EPI == 1) {
                #pragma unroll
                for (int n = 0; n < 8; ++n) {
                    int gc = col0 + n * 16 + l15;
                    float v = acc[m][n][q] + bias[gc];
                    v = fmaxf(v, 0.f);
                    C[(size_t)gr * NN + gc] = f2bf(v);
                }
            } else {
                float sp = 0.f, dp = 0.f;
                #pragma unroll
                for (int n = 0; n < 8; ++n) {
                    int gc = n * 16 + l15;
                    float v = acc[m][n][q];
                    C[(size_t)gr * NN + gc] = f2bf(v);
                    sp += v * va[gc];
                    dp += v * vb[gc];
                }
                #pragma unroll
                for (int off = 1; off < 16; off <<= 1) {
                    sp += __shfl_xor(sp, off);
                    dp += __shfl_xor(dp, off);
                }
                if (l15 == 0) { sOut[gr] = sp; dOut[gr] = dp; }
            }
        }
    }
}

// ---- fused softmax + weighted gather. One wave/node, 8 groups x 8 lanes,
// 2-edge unrolled (16 row loads in flight per wave). No max pass.
// OUTBF: write bf16 (aggx). else: f32 + bias (final output).
template <bool OUTBF>
__global__ __launch_bounds__(256) void node_gather_k(
    const int* __restrict__ rowptr, const int* __restrict__ ssrc,
    const float* __restrict__ s, const float* __restrict__ d,
    const unsigned short* __restrict__ hsrc, const float* __restrict__ bias,
    unsigned short* __restrict__ obf, float* __restrict__ outf, int N) {
    constexpr int F = 128, G = 8;
    const int node = blockIdx.x * 4 + (threadIdx.x >> 6);
    const int lane = threadIdx.x & 63;
    if (node >= N) return;
    const int beg = rowptr[node];
    const int end = rowptr[node + 1];
    const float dn = d[node];
    const int grp = lane >> 3;   // 0..7
    const int lr = lane & 7;     // 0..7 -> 16 bf16 (32B) per lane

    float acc[16] = {};
    float zsum = 0.f;
    int j = beg + grp;
    for (; j + G < end; j += 2 * G) {
        int sj0 = ssrc[j];
        int sj1 = ssrc[j + G];
        float e0 = s[sj0] + dn;
        float e1 = s[sj1] + dn;
        const unsigned short* r0 = hsrc + (size_t)sj0 * F + lr * 16;
        const unsigned short* r1 = hsrc + (size_t)sj1 * F + lr * 16;
        bf16x8 v0a = *(const bf16x8*)r0;
        bf16x8 v0b = *(const bf16x8*)(r0 + 8);
        bf16x8 v1a = *(const bf16x8*)r1;
        bf16x8 v1b = *(const bf16x8*)(r1 + 8);
        e0 = (e0 > 0.f) ? e0 : NEG_SLOPE * e0;
        e1 = (e1 > 0.f) ? e1 : NEG_SLOPE * e1;
        float x0 = __expf(e0);
        float x1 = __expf(e1);
        zsum += x0 + x1;
        #pragma unroll
        for (int q = 0; q < 8; ++q) {
            acc[q]     += x0 * bf2f(((unsigned short*)&v0a)[q]);
            acc[q + 8] += x0 * bf2f(((unsigned short*)&v0b)[q]);
            acc[q]     += x1 * bf2f(((unsigned short*)&v1a)[q]);
            acc[q + 8] += x1 * bf2f(((unsigned short*)&v1b)[q]);
        }
    }
    if (j < end) {
        int sj = ssrc[j];
        float e = s[sj] + dn;
        e = (e > 0.f) ? e : NEG_SLOPE * e;
        float exj = __expf(e);
        zsum += exj;
        const unsigned short* r0 = hsrc + (size_t)sj * F + lr * 16;
        bf16x8 va_ = *(const bf16x8*)r0;
        bf16x8 vb_ = *(const bf16x8*)(r0 + 8);
        #pragma unroll
        for (int q = 0; q < 8; ++q) {
            acc[q]     += exj * bf2f(((unsigned short*)&va_)[q]);
            acc[q + 8] += exj * bf2f(((unsigned short*)&vb_)[q]);
        }
    }
    // reduce across the 8 groups (lanes with equal lr)
    #pragma unroll
    for (int off = 8; off < 64; off <<= 1) {
        zsum += __shfl_xor(zsum, off);
        #pragma unroll
        for (int q = 0; q < 16; ++q) acc[q] += __shfl_xor(acc[q], off);
    }
    const float inv = 1.f / zsum;

    if (lane < 8) {
        if constexpr (OUTBF) {
            bf16x8 w0, w1;
            #pragma unroll
            for (int q = 0; q < 8; ++q) {
                ((unsigned short*)&w0)[q] = f2bf(acc[q] * inv);
                ((unsigned short*)&w1)[q] = f2bf(acc[q + 8] * inv);
            }
            *(bf16x8*)(obf + (size_t)node * F + lr * 16) = w0;
            *(bf16x8*)(obf + (size_t)node * F + lr * 16 + 8) = w1;
        } else {
            float o[16];
            #pragma unroll
            for (int q = 0; q < 16; ++q)
                o[q] = acc[q] * inv + bias[lr * 16 + q];
            float* op = outf + (size_t)node * F + lr * 16;
            *(float4*)op = {o[0], o[1], o[2], o[3]};
            *(float4*)(op + 4) = {o[4], o[5], o[6], o[7]};
            *(float4*)(op + 8) = {o[8], o[9], o[10], o[11]};
            *(float4*)(op + 12) = {o[12], o[13], o[14], o[15]};
        }
    }
}

extern "C" void kernel_launch(void* const* d_in, const int* in_sizes, int n_in,
                              void* d_out, int out_size, void* d_ws, size_t ws_size,
                              hipStream_t stream) {
    const float* x      = (const float*)d_in[0];
    const int*   eidx   = (const int*)d_in[1];
    const float* W1     = (const float*)d_in[2];
    const float* a_src1 = (const float*)d_in[3];
    const float* a_dst1 = (const float*)d_in[4];
    const float* b1     = (const float*)d_in[5];
    const float* W2     = (const float*)d_in[6];
    const float* a_src2 = (const float*)d_in[7];
    const float* a_dst2 = (const float*)d_in[8];
    const float* b2     = (const float*)d_in[9];

    int N = in_sizes[0] / 128;   // 50000
    int E = in_sizes[1] / 2;     // 800000
    const int F_IN = 128, H = 256, F_OUT = 128;
    const int EA = E + N;

    const int* srcE = eidx;
    const int* dstE = eidx + E;

    // ---- workspace layout (~74 MB) ----
    unsigned short* xbf    = (unsigned short*)d_ws;                 // N*128 bf16
    unsigned short* aggx   = xbf + (size_t)N * F_IN;                // N*128 bf16
    unsigned short* g1     = aggx + (size_t)N * F_IN;               // N*256 bf16
    unsigned short* h2bf   = g1 + (size_t)N * H;                    // N*128 bf16
    float*          sbuf   = (float*)(h2bf + (size_t)N * F_OUT);    // N
    float*          dbuf   = sbuf + N;                              // N
    float*          w_s1   = dbuf + N;                              // 128
    float*          w_d1   = w_s1 + F_IN;                           // 128
    unsigned short* w1T    = (unsigned short*)(w_d1 + F_IN);        // 256*128
    unsigned short* w2T    = w1T + 32768;                           // 128*256
    int*            rowptr = (int*)(w2T + 32768);                   // N+1
    int*            cnt    = rowptr + (N + 1);                      // NREP*N
    int*            part   = cnt + NREP * N;                        // 32
    int*            ssrc   = part + 32;                             // E+N
    int*            rank   = ssrc + EA;                             // E+N

    float* out = (float*)d_out;

    // ---------------- cooperative front-end (1 dispatch) ----------------
    {
        void* args[] = {
            (void*)&srcE, (void*)&dstE, (void*)&x, (void*)&W1, (void*)&W2,
            (void*)&a_src1, (void*)&a_dst1, (void*)&cnt, (void*)&rank,
            (void*)&rowptr, (void*)&part, (void*)&ssrc, (void*)&xbf,
            (void*)&w1T, (void*)&w2T, (void*)&w_s1, (void*)&w_d1,
            (void*)&sbuf, (void*)&dbuf, (void*)&E, (void*)&N};
        hipLaunchCooperativeKernel(reinterpret_cast<void*>(fused_pre_k),
                                   dim3(CSR_BLOCKS), dim3(256), args, 0, stream);
    }

    // ---------------- layer 1: gather(x) -> GEMM ----------------
    {
        int nb = (N + 3) / 4;
        node_gather_k<true><<<nb, 256, 0, stream>>>(
            rowptr, ssrc, sbuf, dbuf, xbf, nullptr, aggx, nullptr, N);

        dim3 gg((N + 127) / 128, H / 128);
        gemm_bf16<128, 256, 1><<<gg, 256, 0, stream>>>(
            aggx, w1T, g1, b1, nullptr, nullptr, nullptr, nullptr, N);
    }

    // ---------------- layer 2: GEMM(+rowdots) -> gather(h2) ----------------
    {
        dim3 gg((N + 127) / 128, 1);
        gemm_bf16<256, 128, 2><<<gg, 256, 0, stream>>>(
            g1, w2T, h2bf, nullptr, a_src2, a_dst2, sbuf, dbuf, N);

        int nb = (N + 3) / 4;
        node_gather_k<false><<<nb, 256, 0, stream>>>(
            rowptr, ssrc, sbuf, dbuf, h2bf, b2, nullptr, out, N);
    }
}

// Round 15
// 191.912 us; speedup vs baseline: 2.9308x; 2.9308x over previous
//
#include <hip/hip_runtime.h>
#include <hip/hip_bf16.h>

// ---------------------------------------------------------------------------
// GAT encoder, 2 layers. Round 15: round-13 dispatch structure (12 launches;
// grid.sync proved 25x costlier than dispatch boundaries on MI355X) + the
// round-14 8-lane-group gather (32B/lane, 16 row loads in flight per wave).
// ---------------------------------------------------------------------------

#define NEG_SLOPE 0.2f
#define SCAN_SEG 2048
#define NREP 4

typedef __attribute__((ext_vector_type(8))) short bf16x8;
typedef __attribute__((ext_vector_type(4))) float f32x4;

__device__ __forceinline__ unsigned short f2bf(float v) {
    __hip_bfloat16 b = __float2bfloat16(v);
    return *reinterpret_cast<unsigned short*>(&b);
}
__device__ __forceinline__ float bf2f(unsigned short u) {
    __hip_bfloat16 b = *reinterpret_cast<__hip_bfloat16*>(&u);
    return __bfloat162float(b);
}

// ---- fused: x f32 -> bf16 copy + s,d row dots. One wave per node. ----
__global__ __launch_bounds__(256) void xprep_k(
    const float* __restrict__ x, const float* __restrict__ va,
    const float* __restrict__ vb, unsigned short* __restrict__ xbf,
    float* __restrict__ s, float* __restrict__ d, int N) {
    int w = (blockIdx.x * 256 + threadIdx.x) >> 6;
    int lane = threadIdx.x & 63;
    if (w >= N) return;
    float2 v = *(const float2*)(x + (size_t)w * 128 + lane * 2);
    ushort2 u;
    u.x = f2bf(v.x);
    u.y = f2bf(v.y);
    *(ushort2*)(xbf + (size_t)w * 128 + lane * 2) = u;
    float ss = v.x * va[lane * 2] + v.y * va[lane * 2 + 1];
    float dd = v.x * vb[lane * 2] + v.y * vb[lane * 2 + 1];
    #pragma unroll
    for (int off = 32; off; off >>= 1) {
        ss += __shfl_down(ss, off);
        dd += __shfl_down(dd, off);
    }
    if (lane == 0) { s[w] = ss; d[w] = dd; }
}

// ---- fused weight prep: transposes (f32->bf16) + W1 projection dots ----
// blocks 0..127: W1 transpose; 128..255: W2 transpose; 256..287: proj dots.
__global__ __launch_bounds__(256) void wprep_k(
    const float* __restrict__ W1, const float* __restrict__ W2,
    const float* __restrict__ a_src1, const float* __restrict__ a_dst1,
    unsigned short* __restrict__ w1T, unsigned short* __restrict__ w2T,
    float* __restrict__ w_s1, float* __restrict__ w_d1) {
    const int b = blockIdx.x;
    if (b < 128) {                       // W1[128][256] -> w1T[256][128]
        int i = b * 256 + threadIdx.x;
        int k = i >> 8, n = i & 255;
        w1T[n * 128 + k] = f2bf(W1[i]);
    } else if (b < 256) {                // W2[256][128] -> w2T[128][256]
        int j = (b - 128) * 256 + threadIdx.x;
        int k = j >> 7, n = j & 127;
        w2T[n * 256 + k] = f2bf(W2[j]);
    } else {                             // w_s1[f]=W1[f]·a_src1, w_d1 likewise
        int w = ((b - 256) * 256 + threadIdx.x) >> 6;  // 0..127
        int lane = threadIdx.x & 63;
        const float* row = W1 + (size_t)w * 256;
        float ss = 0.f, dd = 0.f;
        #pragma unroll
        for (int f = lane; f < 256; f += 64) {
            float v = row[f];
            ss += v * a_src1[f];
            dd += v * a_dst1[f];
        }
        #pragma unroll
        for (int off = 32; off; off >>= 1) {
            ss += __shfl_down(ss, off);
            dd += __shfl_down(dd, off);
        }
        if (lane == 0) { w_s1[w] = ss; w_d1[w] = dd; }
    }
}

// ---- bf16 MFMA GEMM, BM=128 BN=128 BK=32, 4 waves (32 rows x 128 cols each).
// EPI=1: relu(acc+bias[col]) -> bf16 C. EPI=2: bf16 C + in-register rowdots
//        sOut[row]=C_row·va, dOut[row]=C_row·vb (BN==NN: full rows in block).
template <int K, int NN, int EPI>
__global__ __launch_bounds__(256) void gemm_bf16(
    const unsigned short* __restrict__ A, const unsigned short* __restrict__ BT,
    unsigned short* __restrict__ C, const float* __restrict__ bias,
    const float* __restrict__ va, const float* __restrict__ vb,
    float* __restrict__ sOut, float* __restrict__ dOut, int M) {
    constexpr int BK = 32, PAD = 8;
    __shared__ short As[128][BK + PAD];
    __shared__ short Bs[128][BK + PAD];
    const int tid = threadIdx.x;
    const int wv = tid >> 6;
    const int ln = tid & 63;
    const int row0 = blockIdx.x * 128;
    const int col0 = blockIdx.y * 128;

    f32x4 acc[2][8];
    #pragma unroll
    for (int m = 0; m < 2; ++m)
        #pragma unroll
        for (int n = 0; n < 8; ++n) acc[m][n] = {0.f, 0.f, 0.f, 0.f};

    const int l15 = ln & 15;
    const int kg = (ln >> 4) * 8;

    for (int k0 = 0; k0 < K; k0 += BK) {
        #pragma unroll
        for (int t = 0; t < 2; ++t) {
            int v = tid + t * 256;
            int r = v >> 2;
            int kc = (v & 3) * 8;
            bf16x8 val = {0, 0, 0, 0, 0, 0, 0, 0};
            int gr = row0 + r;
            if (gr < M)
                val = *(const bf16x8*)(A + (size_t)gr * K + k0 + kc);
            *(bf16x8*)(&As[r][kc]) = val;
        }
        #pragma unroll
        for (int t = 0; t < 2; ++t) {
            int v = tid + t * 256;
            int c = v >> 2;
            int kc = (v & 3) * 8;
            *(bf16x8*)(&Bs[c][kc]) =
                *(const bf16x8*)(BT + (size_t)(col0 + c) * K + k0 + kc);
        }
        __syncthreads();

        bf16x8 ah[2], bh[8];
        #pragma unroll
        for (int m = 0; m < 2; ++m)
            ah[m] = *(const bf16x8*)&As[wv * 32 + m * 16 + l15][kg];
        #pragma unroll
        for (int n = 0; n < 8; ++n)
            bh[n] = *(const bf16x8*)&Bs[n * 16 + l15][kg];
        #pragma unroll
        for (int m = 0; m < 2; ++m)
            #pragma unroll
            for (int n = 0; n < 8; ++n)
                acc[m][n] = __builtin_amdgcn_mfma_f32_16x16x32_bf16(
                    ah[m], bh[n], acc[m][n], 0, 0, 0);
        __syncthreads();
    }

    // C/D layout: col=lane&15, row=(lane>>4)*4+reg
    const int crow = (ln >> 4) * 4;
    #pragma unroll
    for (int m = 0; m < 2; ++m) {
        #pragma unroll
        for (int q = 0; q < 4; ++q) {
            int gr = row0 + wv * 32 + m * 16 + crow + q;
            if (gr >= M) continue;
            if constexpr (EPI == 1) {
                #pragma unroll
                for (int n = 0; n < 8; ++n) {
                    int gc = col0 + n * 16 + l15;
                    float v = acc[m][n][q] + bias[gc];
                    v = fmaxf(v, 0.f);
                    C[(size_t)gr * NN + gc] = f2bf(v);
                }
            } else {
                float sp = 0.f, dp = 0.f;
                #pragma unroll
                for (int n = 0; n < 8; ++n) {
                    int gc = n * 16 + l15;
                    float v = acc[m][n][q];
                    C[(size_t)gr * NN + gc] = f2bf(v);
                    sp += v * va[gc];
                    dp += v * vb[gc];
                }
                #pragma unroll
                for (int off = 1; off < 16; off <<= 1) {
                    sp += __shfl_xor(sp, off);
                    dp += __shfl_xor(dp, off);
                }
                if (l15 == 0) { sOut[gr] = sp; dOut[gr] = dp; }
            }
        }
    }
}

// ---- CSR pass A: replicated-counter rank. rank=(local<<2)|rep ----
#define RANK_VPT 4
__global__ __launch_bounds__(256) void rank_k(
    const int* __restrict__ dstE, int* __restrict__ cnt,
    int* __restrict__ rank, int E, int N, int stride) {
    const int i0 = blockIdx.x * 256 + threadIdx.x;
    const int rep = threadIdx.x & (NREP - 1);
    const int total = E + N;
    int idx[RANK_VPT], di[RANK_VPT], r[RANK_VPT];
    #pragma unroll
    for (int k = 0; k < RANK_VPT; ++k) {
        idx[k] = i0 + k * stride;
        if (idx[k] < total)
            di[k] = (idx[k] < E) ? dstE[idx[k]] : idx[k] - E;
    }
    #pragma unroll
    for (int k = 0; k < RANK_VPT; ++k)
        if (idx[k] < total) r[k] = atomicAdd(&cnt[rep * N + di[k]], 1);
    #pragma unroll
    for (int k = 0; k < RANK_VPT; ++k)
        if (idx[k] < total) rank[idx[k]] = (r[k] << 2) | rep;
}

// ---- CSR pass C: batched atomic-free placement ----
#define PLACE_VPT 4
__global__ __launch_bounds__(256) void place_k(
    const int* __restrict__ srcE, const int* __restrict__ dstE,
    const int* __restrict__ base, const int* __restrict__ rank,
    int* __restrict__ ssrc, int E, int N, int stride) {
    const int i0 = blockIdx.x * 256 + threadIdx.x;
    const int total = E + N;
    int idx[PLACE_VPT], si[PLACE_VPT], di[PLACE_VPT], pk[PLACE_VPT];
    #pragma unroll
    for (int k = 0; k < PLACE_VPT; ++k) {
        idx[k] = i0 + k * stride;
        if (idx[k] < total) {
            if (idx[k] < E) { si[k] = srcE[idx[k]]; di[k] = dstE[idx[k]]; }
            else            { si[k] = di[k] = idx[k] - E; }
            pk[k] = rank[idx[k]];
        }
    }
    int pos[PLACE_VPT];
    #pragma unroll
    for (int k = 0; k < PLACE_VPT; ++k)
        if (idx[k] < total) pos[k] = base[(pk[k] & 3) * N + di[k]];
    #pragma unroll
    for (int k = 0; k < PLACE_VPT; ++k)
        if (idx[k] < total) ssrc[pos[k] + (pk[k] >> 2)] = si[k];
}

// ---- 3-phase multi-block exclusive scan (over 4-replica totals) ----
__global__ __launch_bounds__(256) void scan_part_k(
    const int* __restrict__ cnt, int* __restrict__ part, int N) {
    __shared__ int wsum[4];
    const int base = blockIdx.x * SCAN_SEG;
    const int lim = min(base + SCAN_SEG, N);
    int s = 0;
    for (int i = base + threadIdx.x; i < lim; i += 256)
        s += cnt[i] + cnt[N + i] + cnt[2 * N + i] + cnt[3 * N + i];
    #pragma unroll
    for (int off = 32; off; off >>= 1) s += __shfl_down(s, off);
    if ((threadIdx.x & 63) == 0) wsum[threadIdx.x >> 6] = s;
    __syncthreads();
    if (threadIdx.x == 0) part[blockIdx.x] = wsum[0] + wsum[1] + wsum[2] + wsum[3];
}

__global__ void scan_offsets_k(int* __restrict__ part, int nseg,
                               int* __restrict__ rowptr, int N) {
    if (threadIdx.x == 0) {
        int run = 0;
        for (int i = 0; i < nseg; ++i) { int c = part[i]; part[i] = run; run += c; }
        rowptr[N] = run;
    }
}

// writes rowptr and converts cnt[r][i] into absolute base offsets
__global__ __launch_bounds__(256) void scan_write_k(
    int* __restrict__ cnt, int* __restrict__ rowptr,
    const int* __restrict__ part, int N) {
    __shared__ int wsum[4];
    const int tid = threadIdx.x;
    const int lane = tid & 63;
    const int wv = tid >> 6;
    const int tbase = blockIdx.x * SCAN_SEG + tid * 8;
    int local[8];
    int s = 0;
    #pragma unroll
    for (int q = 0; q < 8; ++q) {
        int idx = tbase + q;
        int tot = 0;
        if (idx < N)
            tot = cnt[idx] + cnt[N + idx] + cnt[2 * N + idx] + cnt[3 * N + idx];
        local[q] = s;
        s += tot;
    }
    int incl = s;
    #pragma unroll
    for (int off = 1; off < 64; off <<= 1) {
        int t = __shfl_up(incl, off);
        if (lane >= off) incl += t;
    }
    if (lane == 63) wsum[wv] = incl;
    __syncthreads();
    if (tid == 0) {
        int r = 0;
        #pragma unroll
        for (int i = 0; i < 4; ++i) { int c = wsum[i]; wsum[i] = r; r += c; }
    }
    __syncthreads();
    const int base = part[blockIdx.x] + wsum[wv] + (incl - s);
    #pragma unroll
    for (int q = 0; q < 8; ++q) {
        int idx = tbase + q;
        if (idx < N) {
            int pos = base + local[q];
            rowptr[idx] = pos;
            int c0 = cnt[idx], c1 = cnt[N + idx], c2 = cnt[2 * N + idx];
            cnt[idx] = pos;
            cnt[N + idx] = pos + c0;
            cnt[2 * N + idx] = pos + c0 + c1;
            cnt[3 * N + idx] = pos + c0 + c1 + c2;
        }
    }
}

// ---- fused softmax + weighted gather. One wave/node, 8 groups x 8 lanes,
// 2-edge unrolled (16 row loads in flight per wave). No max pass.
// OUTBF: write bf16 (aggx). else: f32 + bias (final output).
template <bool OUTBF>
__global__ __launch_bounds__(256) void node_gather_k(
    const int* __restrict__ rowptr, const int* __restrict__ ssrc,
    const float* __restrict__ s, const float* __restrict__ d,
    const unsigned short* __restrict__ hsrc, const float* __restrict__ bias,
    unsigned short* __restrict__ obf, float* __restrict__ outf, int N) {
    constexpr int F = 128, G = 8;
    const int node = blockIdx.x * 4 + (threadIdx.x >> 6);
    const int lane = threadIdx.x & 63;
    if (node >= N) return;
    const int beg = rowptr[node];
    const int end = rowptr[node + 1];
    const float dn = d[node];
    const int grp = lane >> 3;   // 0..7
    const int lr = lane & 7;     // 0..7 -> 16 bf16 (32B) per lane

    float acc[16] = {};
    float zsum = 0.f;
    int j = beg + grp;
    for (; j + G < end; j += 2 * G) {
        int sj0 = ssrc[j];
        int sj1 = ssrc[j + G];
        float e0 = s[sj0] + dn;
        float e1 = s[sj1] + dn;
        const unsigned short* r0 = hsrc + (size_t)sj0 * F + lr * 16;
        const unsigned short* r1 = hsrc + (size_t)sj1 * F + lr * 16;
        bf16x8 v0a = *(const bf16x8*)r0;
        bf16x8 v0b = *(const bf16x8*)(r0 + 8);
        bf16x8 v1a = *(const bf16x8*)r1;
        bf16x8 v1b = *(const bf16x8*)(r1 + 8);
        e0 = (e0 > 0.f) ? e0 : NEG_SLOPE * e0;
        e1 = (e1 > 0.f) ? e1 : NEG_SLOPE * e1;
        float x0 = __expf(e0);
        float x1 = __expf(e1);
        zsum += x0 + x1;
        #pragma unroll
        for (int q = 0; q < 8; ++q) {
            acc[q]     += x0 * bf2f(((unsigned short*)&v0a)[q]);
            acc[q + 8] += x0 * bf2f(((unsigned short*)&v0b)[q]);
            acc[q]     += x1 * bf2f(((unsigned short*)&v1a)[q]);
            acc[q + 8] += x1 * bf2f(((unsigned short*)&v1b)[q]);
        }
    }
    if (j < end) {
        int sj = ssrc[j];
        float e = s[sj] + dn;
        e = (e > 0.f) ? e : NEG_SLOPE * e;
        float exj = __expf(e);
        zsum += exj;
        const unsigned short* r0 = hsrc + (size_t)sj * F + lr * 16;
        bf16x8 va_ = *(const bf16x8*)r0;
        bf16x8 vb_ = *(const bf16x8*)(r0 + 8);
        #pragma unroll
        for (int q = 0; q < 8; ++q) {
            acc[q]     += exj * bf2f(((unsigned short*)&va_)[q]);
            acc[q + 8] += exj * bf2f(((unsigned short*)&vb_)[q]);
        }
    }
    // reduce across the 8 groups (lanes with equal lr)
    #pragma unroll
    for (int off = 8; off < 64; off <<= 1) {
        zsum += __shfl_xor(zsum, off);
        #pragma unroll
        for (int q = 0; q < 16; ++q) acc[q] += __shfl_xor(acc[q], off);
    }
    const float inv = 1.f / zsum;

    if (lane < 8) {
        if constexpr (OUTBF) {
            bf16x8 w0, w1;
            #pragma unroll
            for (int q = 0; q < 8; ++q) {
                ((unsigned short*)&w0)[q] = f2bf(acc[q] * inv);
                ((unsigned short*)&w1)[q] = f2bf(acc[q + 8] * inv);
            }
            *(bf16x8*)(obf + (size_t)node * F + lr * 16) = w0;
            *(bf16x8*)(obf + (size_t)node * F + lr * 16 + 8) = w1;
        } else {
            float o[16];
            #pragma unroll
            for (int q = 0; q < 16; ++q)
                o[q] = acc[q] * inv + bias[lr * 16 + q];
            float* op = outf + (size_t)node * F + lr * 16;
            *(float4*)op = {o[0], o[1], o[2], o[3]};
            *(float4*)(op + 4) = {o[4], o[5], o[6], o[7]};
            *(float4*)(op + 8) = {o[8], o[9], o[10], o[11]};
            *(float4*)(op + 12) = {o[12], o[13], o[14], o[15]};
        }
    }
}

extern "C" void kernel_launch(void* const* d_in, const int* in_sizes, int n_in,
                              void* d_out, int out_size, void* d_ws, size_t ws_size,
                              hipStream_t stream) {
    const float* x      = (const float*)d_in[0];
    const int*   eidx   = (const int*)d_in[1];
    const float* W1     = (const float*)d_in[2];
    const float* a_src1 = (const float*)d_in[3];
    const float* a_dst1 = (const float*)d_in[4];
    const float* b1     = (const float*)d_in[5];
    const float* W2     = (const float*)d_in[6];
    const float* a_src2 = (const float*)d_in[7];
    const float* a_dst2 = (const float*)d_in[8];
    const float* b2     = (const float*)d_in[9];

    const int N = in_sizes[0] / 128;   // 50000
    const int E = in_sizes[1] / 2;     // 800000
    const int F_IN = 128, H = 256, F_OUT = 128;
    const int EA = E + N;

    const int* srcE = eidx;
    const int* dstE = eidx + E;

    // ---- workspace layout (~74 MB) ----
    unsigned short* xbf    = (unsigned short*)d_ws;                 // N*128 bf16
    unsigned short* aggx   = xbf + (size_t)N * F_IN;                // N*128 bf16
    unsigned short* g1     = aggx + (size_t)N * F_IN;               // N*256 bf16
    unsigned short* h2bf   = g1 + (size_t)N * H;                    // N*128 bf16
    float*          sbuf   = (float*)(h2bf + (size_t)N * F_OUT);    // N
    float*          dbuf   = sbuf + N;                              // N
    float*          w_s1   = dbuf + N;                              // 128
    float*          w_d1   = w_s1 + F_IN;                           // 128
    unsigned short* w1T    = (unsigned short*)(w_d1 + F_IN);        // 256*128
    unsigned short* w2T    = w1T + 32768;                           // 128*256
    int*            rowptr = (int*)(w2T + 32768);                   // N+1
    int*            cnt    = rowptr + (N + 1);                      // NREP*N
    int*            part   = cnt + NREP * N;                        // 32
    int*            ssrc   = part + 32;                             // E+N
    int*            rank   = ssrc + EA;                             // E+N

    float* out = (float*)d_out;

    // ---------------- CSR build ----------------
    {
        hipMemsetAsync(cnt, 0, (size_t)NREP * N * 4, stream);
        int stride = (EA + RANK_VPT - 1) / RANK_VPT;
        int rblocks = (stride + 255) / 256;
        stride = rblocks * 256;
        rank_k<<<rblocks, 256, 0, stream>>>(dstE, cnt, rank, E, N, stride);
        int nseg = (N + SCAN_SEG - 1) / SCAN_SEG;
        scan_part_k<<<nseg, 256, 0, stream>>>(cnt, part, N);
        scan_offsets_k<<<1, 64, 0, stream>>>(part, nseg, rowptr, N);
        scan_write_k<<<nseg, 256, 0, stream>>>(cnt, rowptr, part, N);
        place_k<<<rblocks, 256, 0, stream>>>(srcE, dstE, cnt, rank, ssrc, E, N, stride);
    }

    // ---------------- prep: transposes + projections (one kernel) ----------
    wprep_k<<<288, 256, 0, stream>>>(W1, W2, a_src1, a_dst1, w1T, w2T, w_s1, w_d1);

    // ---------------- layer 1: xprep -> gather(x) -> GEMM ----------------
    {
        int rb = (N * 64 + 255) / 256;
        xprep_k<<<rb, 256, 0, stream>>>(x, w_s1, w_d1, xbf, sbuf, dbuf, N);

        int nb = (N + 3) / 4;
        node_gather_k<true><<<nb, 256, 0, stream>>>(
            rowptr, ssrc, sbuf, dbuf, xbf, nullptr, aggx, nullptr, N);

        dim3 gg((N + 127) / 128, H / 128);
        gemm_bf16<128, 256, 1><<<gg, 256, 0, stream>>>(
            aggx, w1T, g1, b1, nullptr, nullptr, nullptr, nullptr, N);
    }

    // ---------------- layer 2: GEMM(+rowdots) -> gather(h2) ----------------
    {
        dim3 gg((N + 127) / 128, 1);
        gemm_bf16<256, 128, 2><<<gg, 256, 0, stream>>>(
            g1, w2T, h2bf, nullptr, a_src2, a_dst2, sbuf, dbuf, N);

        int nb = (N + 3) / 4;
        node_gather_k<false><<<nb, 256, 0, stream>>>(
            rowptr, ssrc, sbuf, dbuf, h2bf, b2, nullptr, out, N);
    }
}

// Round 16
// 178.386 us; speedup vs baseline: 3.1530x; 1.0758x over previous
//
#include <hip/hip_runtime.h>
#include <hip/hip_bf16.h>

// ---------------------------------------------------------------------------
// GAT encoder, 2 layers. Round 16: round-15 kernels, dispatch-graph surgery:
//  - cnt zeroing folded into wprep (memset dispatch gone)
//  - rank + xprep merged into one kernel (independent work; atomic-latency
//    blocks overlap with BW-bound x-prep blocks)
//  - scan_offsets folded into scan_write (in-block 25-seg shfl prefix)
// 9 dispatches total. (grid.sync ruled out: ~100us/sync on 8-XCD MI355X.)
// ---------------------------------------------------------------------------

#define NEG_SLOPE 0.2f
#define SCAN_SEG 2048
#define NREP 4
#define RANK_BLOCKS 832   // 832*256*4 >= E+N = 850000

typedef __attribute__((ext_vector_type(8))) short bf16x8;
typedef __attribute__((ext_vector_type(4))) float f32x4;

__device__ __forceinline__ unsigned short f2bf(float v) {
    __hip_bfloat16 b = __float2bfloat16(v);
    return *reinterpret_cast<unsigned short*>(&b);
}
__device__ __forceinline__ float bf2f(unsigned short u) {
    __hip_bfloat16 b = *reinterpret_cast<__hip_bfloat16*>(&u);
    return __bfloat162float(b);
}

// ---- weight prep + cnt zero. blocks 0..127: W1T; 128..255: W2T;
//      256..287: W1 projection dots. All blocks: grid-stride zero of cnt. ----
__global__ __launch_bounds__(256) void wprep_k(
    const float* __restrict__ W1, const float* __restrict__ W2,
    const float* __restrict__ a_src1, const float* __restrict__ a_dst1,
    unsigned short* __restrict__ w1T, unsigned short* __restrict__ w2T,
    float* __restrict__ w_s1, float* __restrict__ w_d1,
    int* __restrict__ cnt, int N) {
    const int b = blockIdx.x;
    for (int i = b * 256 + threadIdx.x; i < NREP * N; i += gridDim.x * 256)
        cnt[i] = 0;
    if (b < 128) {                       // W1[128][256] -> w1T[256][128]
        int i = b * 256 + threadIdx.x;
        int k = i >> 8, n = i & 255;
        w1T[n * 128 + k] = f2bf(W1[i]);
    } else if (b < 256) {                // W2[256][128] -> w2T[128][256]
        int j = (b - 128) * 256 + threadIdx.x;
        int k = j >> 7, n = j & 127;
        w2T[n * 256 + k] = f2bf(W2[j]);
    } else if (b < 288) {                // w_s1[f]=W1[f]·a_src1, w_d1 likewise
        int w = ((b - 256) * 256 + threadIdx.x) >> 6;  // 0..127
        int lane = threadIdx.x & 63;
        const float* row = W1 + (size_t)w * 256;
        float ss = 0.f, dd = 0.f;
        #pragma unroll
        for (int f = lane; f < 256; f += 64) {
            float v = row[f];
            ss += v * a_src1[f];
            dd += v * a_dst1[f];
        }
        #pragma unroll
        for (int off = 32; off; off >>= 1) {
            ss += __shfl_down(ss, off);
            dd += __shfl_down(dd, off);
        }
        if (lane == 0) { w_s1[w] = ss; w_d1[w] = dd; }
    }
}

// ---- merged rank + xprep. blocks [0,RANK_BLOCKS): replicated-counter rank
//      (VPT=4, rank=(local<<2)|rep). blocks [RANK_BLOCKS, ...): x->bf16 +
//      s/d row dots (one wave per node). Independent work, co-resident. ----
__global__ __launch_bounds__(256) void rank_xprep_k(
    const int* __restrict__ dstE, int* __restrict__ cnt, int* __restrict__ rank,
    const float* __restrict__ x, const float* __restrict__ va,
    const float* __restrict__ vb, unsigned short* __restrict__ xbf,
    float* __restrict__ s, float* __restrict__ d, int E, int N) {
    const int b = blockIdx.x;
    if (b < RANK_BLOCKS) {
        const int stride = RANK_BLOCKS * 256;
        const int i0 = b * 256 + threadIdx.x;
        const int rep = threadIdx.x & (NREP - 1);
        const int total = E + N;
        int idx[4], di[4], r[4];
        #pragma unroll
        for (int k = 0; k < 4; ++k) {
            idx[k] = i0 + k * stride;
            if (idx[k] < total)
                di[k] = (idx[k] < E) ? dstE[idx[k]] : idx[k] - E;
        }
        #pragma unroll
        for (int k = 0; k < 4; ++k)
            if (idx[k] < total) r[k] = atomicAdd(&cnt[rep * N + di[k]], 1);
        #pragma unroll
        for (int k = 0; k < 4; ++k)
            if (idx[k] < total) rank[idx[k]] = (r[k] << 2) | rep;
    } else {
        int w = (((b - RANK_BLOCKS) * 256) + threadIdx.x) >> 6;
        int lane = threadIdx.x & 63;
        if (w >= N) return;
        float2 v = *(const float2*)(x + (size_t)w * 128 + lane * 2);
        ushort2 u;
        u.x = f2bf(v.x);
        u.y = f2bf(v.y);
        *(ushort2*)(xbf + (size_t)w * 128 + lane * 2) = u;
        float ss = v.x * va[lane * 2] + v.y * va[lane * 2 + 1];
        float dd = v.x * vb[lane * 2] + v.y * vb[lane * 2 + 1];
        #pragma unroll
        for (int off = 32; off; off >>= 1) {
            ss += __shfl_down(ss, off);
            dd += __shfl_down(dd, off);
        }
        if (lane == 0) { s[w] = ss; d[w] = dd; }
    }
}

// ---- scan phase 1: per-segment 4-replica totals -> part[] ----
__global__ __launch_bounds__(256) void scan_part_k(
    const int* __restrict__ cnt, int* __restrict__ part, int N) {
    __shared__ int wsum[4];
    const int base = blockIdx.x * SCAN_SEG;
    const int lim = min(base + SCAN_SEG, N);
    int s = 0;
    for (int i = base + threadIdx.x; i < lim; i += 256)
        s += cnt[i] + cnt[N + i] + cnt[2 * N + i] + cnt[3 * N + i];
    #pragma unroll
    for (int off = 32; off; off >>= 1) s += __shfl_down(s, off);
    if ((threadIdx.x & 63) == 0) wsum[threadIdx.x >> 6] = s;
    __syncthreads();
    if (threadIdx.x == 0) part[blockIdx.x] = wsum[0] + wsum[1] + wsum[2] + wsum[3];
}

// ---- scan phase 2: in-block part prefix + rowptr + absolute replica bases ----
__global__ __launch_bounds__(256) void scan_write_k(
    int* __restrict__ cnt, int* __restrict__ rowptr,
    const int* __restrict__ part, int nseg, int N) {
    __shared__ int wsum[4];
    __shared__ int pbase_s, ptot_s;
    const int tid = threadIdx.x;
    // prefix over part[] (nseg <= 64) in lanes 0..63 of wave 0
    if (tid < 64) {
        int v = (tid < nseg) ? part[tid] : 0;
        int incl = v;
        #pragma unroll
        for (int off = 1; off < 64; off <<= 1) {
            int t = __shfl_up(incl, off);
            if (tid >= off) incl += t;
        }
        if (tid == (int)blockIdx.x) pbase_s = incl - v;
        if (tid == 63) ptot_s = incl;
    }
    __syncthreads();
    const int lane = tid & 63;
    const int wv = tid >> 6;
    const int tbase = blockIdx.x * SCAN_SEG + tid * 8;
    int local[8];
    int s = 0;
    #pragma unroll
    for (int q = 0; q < 8; ++q) {
        int idx = tbase + q;
        int tot = 0;
        if (idx < N)
            tot = cnt[idx] + cnt[N + idx] + cnt[2 * N + idx] + cnt[3 * N + idx];
        local[q] = s;
        s += tot;
    }
    int incl = s;
    #pragma unroll
    for (int off = 1; off < 64; off <<= 1) {
        int t = __shfl_up(incl, off);
        if (lane >= off) incl += t;
    }
    if (lane == 63) wsum[wv] = incl;
    __syncthreads();
    if (tid == 0) {
        int r = 0;
        #pragma unroll
        for (int i = 0; i < 4; ++i) { int c = wsum[i]; wsum[i] = r; r += c; }
    }
    __syncthreads();
    const int base = pbase_s + wsum[wv] + (incl - s);
    #pragma unroll
    for (int q = 0; q < 8; ++q) {
        int idx = tbase + q;
        if (idx < N) {
            int pos = base + local[q];
            rowptr[idx] = pos;
            int c0 = cnt[idx], c1 = cnt[N + idx], c2 = cnt[2 * N + idx];
            cnt[idx] = pos;
            cnt[N + idx] = pos + c0;
            cnt[2 * N + idx] = pos + c0 + c1;
            cnt[3 * N + idx] = pos + c0 + c1 + c2;
        }
    }
    if (blockIdx.x == 0 && tid == 0) rowptr[N] = ptot_s;
}

// ---- CSR pass C: batched atomic-free placement ----
__global__ __launch_bounds__(256) void place_k(
    const int* __restrict__ srcE, const int* __restrict__ dstE,
    const int* __restrict__ base, const int* __restrict__ rank,
    int* __restrict__ ssrc, int E, int N) {
    const int stride = RANK_BLOCKS * 256;
    const int i0 = blockIdx.x * 256 + threadIdx.x;
    const int total = E + N;
    int idx[4], si[4], di[4], pk[4];
    #pragma unroll
    for (int k = 0; k < 4; ++k) {
        idx[k] = i0 + k * stride;
        if (idx[k] < total) {
            if (idx[k] < E) { si[k] = srcE[idx[k]]; di[k] = dstE[idx[k]]; }
            else            { si[k] = di[k] = idx[k] - E; }
            pk[k] = rank[idx[k]];
        }
    }
    int pos[4];
    #pragma unroll
    for (int k = 0; k < 4; ++k)
        if (idx[k] < total) pos[k] = base[(pk[k] & 3) * N + di[k]];
    #pragma unroll
    for (int k = 0; k < 4; ++k)
        if (idx[k] < total) ssrc[pos[k] + (pk[k] >> 2)] = si[k];
}

// ---- bf16 MFMA GEMM, BM=128 BN=128 BK=32, 4 waves (32 rows x 128 cols each).
// EPI=1: relu(acc+bias[col]) -> bf16 C. EPI=2: bf16 C + in-register rowdots.
template <int K, int NN, int EPI>
__global__ __launch_bounds__(256) void gemm_bf16(
    const unsigned short* __restrict__ A, const unsigned short* __restrict__ BT,
    unsigned short* __restrict__ C, const float* __restrict__ bias,
    const float* __restrict__ va, const float* __restrict__ vb,
    float* __restrict__ sOut, float* __restrict__ dOut, int M) {
    constexpr int BK = 32, PAD = 8;
    __shared__ short As[128][BK + PAD];
    __shared__ short Bs[128][BK + PAD];
    const int tid = threadIdx.x;
    const int wv = tid >> 6;
    const int ln = tid & 63;
    const int row0 = blockIdx.x * 128;
    const int col0 = blockIdx.y * 128;

    f32x4 acc[2][8];
    #pragma unroll
    for (int m = 0; m < 2; ++m)
        #pragma unroll
        for (int n = 0; n < 8; ++n) acc[m][n] = {0.f, 0.f, 0.f, 0.f};

    const int l15 = ln & 15;
    const int kg = (ln >> 4) * 8;

    for (int k0 = 0; k0 < K; k0 += BK) {
        #pragma unroll
        for (int t = 0; t < 2; ++t) {
            int v = tid + t * 256;
            int r = v >> 2;
            int kc = (v & 3) * 8;
            bf16x8 val = {0, 0, 0, 0, 0, 0, 0, 0};
            int gr = row0 + r;
            if (gr < M)
                val = *(const bf16x8*)(A + (size_t)gr * K + k0 + kc);
            *(bf16x8*)(&As[r][kc]) = val;
        }
        #pragma unroll
        for (int t = 0; t < 2; ++t) {
            int v = tid + t * 256;
            int c = v >> 2;
            int kc = (v & 3) * 8;
            *(bf16x8*)(&Bs[c][kc]) =
                *(const bf16x8*)(BT + (size_t)(col0 + c) * K + k0 + kc);
        }
        __syncthreads();

        bf16x8 ah[2], bh[8];
        #pragma unroll
        for (int m = 0; m < 2; ++m)
            ah[m] = *(const bf16x8*)&As[wv * 32 + m * 16 + l15][kg];
        #pragma unroll
        for (int n = 0; n < 8; ++n)
            bh[n] = *(const bf16x8*)&Bs[n * 16 + l15][kg];
        #pragma unroll
        for (int m = 0; m < 2; ++m)
            #pragma unroll
            for (int n = 0; n < 8; ++n)
                acc[m][n] = __builtin_amdgcn_mfma_f32_16x16x32_bf16(
                    ah[m], bh[n], acc[m][n], 0, 0, 0);
        __syncthreads();
    }

    // C/D layout: col=lane&15, row=(lane>>4)*4+reg
    const int crow = (ln >> 4) * 4;
    #pragma unroll
    for (int m = 0; m < 2; ++m) {
        #pragma unroll
        for (int q = 0; q < 4; ++q) {
            int gr = row0 + wv * 32 + m * 16 + crow + q;
            if (gr >= M) continue;
            if constexpr (EPI == 1) {
                #pragma unroll
                for (int n = 0; n < 8; ++n) {
                    int gc = col0 + n * 16 + l15;
                    float v = acc[m][n][q] + bias[gc];
                    v = fmaxf(v, 0.f);
                    C[(size_t)gr * NN + gc] = f2bf(v);
                }
            } else {
                float sp = 0.f, dp = 0.f;
                #pragma unroll
                for (int n = 0; n < 8; ++n) {
                    int gc = n * 16 + l15;
                    float v = acc[m][n][q];
                    C[(size_t)gr * NN + gc] = f2bf(v);
                    sp += v * va[gc];
                    dp += v * vb[gc];
                }
                #pragma unroll
                for (int off = 1; off < 16; off <<= 1) {
                    sp += __shfl_xor(sp, off);
                    dp += __shfl_xor(dp, off);
                }
                if (l15 == 0) { sOut[gr] = sp; dOut[gr] = dp; }
            }
        }
    }
}

// ---- fused softmax + weighted gather. One wave/node, 8 groups x 8 lanes,
// 2-edge unrolled. No max pass (logits bounded; softmax shift-invariant).
// OUTBF: write bf16 (aggx). else: f32 + bias (final output).
template <bool OUTBF>
__global__ __launch_bounds__(256) void node_gather_k(
    const int* __restrict__ rowptr, const int* __restrict__ ssrc,
    const float* __restrict__ s, const float* __restrict__ d,
    const unsigned short* __restrict__ hsrc, const float* __restrict__ bias,
    unsigned short* __restrict__ obf, float* __restrict__ outf, int N) {
    constexpr int F = 128, G = 8;
    const int node = blockIdx.x * 4 + (threadIdx.x >> 6);
    const int lane = threadIdx.x & 63;
    if (node >= N) return;
    const int beg = rowptr[node];
    const int end = rowptr[node + 1];
    const float dn = d[node];
    const int grp = lane >> 3;   // 0..7
    const int lr = lane & 7;     // 0..7 -> 16 bf16 (32B) per lane

    float acc[16] = {};
    float zsum = 0.f;
    int j = beg + grp;
    for (; j + G < end; j += 2 * G) {
        int sj0 = ssrc[j];
        int sj1 = ssrc[j + G];
        float e0 = s[sj0] + dn;
        float e1 = s[sj1] + dn;
        const unsigned short* r0 = hsrc + (size_t)sj0 * F + lr * 16;
        const unsigned short* r1 = hsrc + (size_t)sj1 * F + lr * 16;
        bf16x8 v0a = *(const bf16x8*)r0;
        bf16x8 v0b = *(const bf16x8*)(r0 + 8);
        bf16x8 v1a = *(const bf16x8*)r1;
        bf16x8 v1b = *(const bf16x8*)(r1 + 8);
        e0 = (e0 > 0.f) ? e0 : NEG_SLOPE * e0;
        e1 = (e1 > 0.f) ? e1 : NEG_SLOPE * e1;
        float x0 = __expf(e0);
        float x1 = __expf(e1);
        zsum += x0 + x1;
        #pragma unroll
        for (int q = 0; q < 8; ++q) {
            acc[q]     += x0 * bf2f(((unsigned short*)&v0a)[q]);
            acc[q + 8] += x0 * bf2f(((unsigned short*)&v0b)[q]);
            acc[q]     += x1 * bf2f(((unsigned short*)&v1a)[q]);
            acc[q + 8] += x1 * bf2f(((unsigned short*)&v1b)[q]);
        }
    }
    if (j < end) {
        int sj = ssrc[j];
        float e = s[sj] + dn;
        e = (e > 0.f) ? e : NEG_SLOPE * e;
        float exj = __expf(e);
        zsum += exj;
        const unsigned short* r0 = hsrc + (size_t)sj * F + lr * 16;
        bf16x8 va_ = *(const bf16x8*)r0;
        bf16x8 vb_ = *(const bf16x8*)(r0 + 8);
        #pragma unroll
        for (int q = 0; q < 8; ++q) {
            acc[q]     += exj * bf2f(((unsigned short*)&va_)[q]);
            acc[q + 8] += exj * bf2f(((unsigned short*)&vb_)[q]);
        }
    }
    // reduce across the 8 groups (lanes with equal lr)
    #pragma unroll
    for (int off = 8; off < 64; off <<= 1) {
        zsum += __shfl_xor(zsum, off);
        #pragma unroll
        for (int q = 0; q < 16; ++q) acc[q] += __shfl_xor(acc[q], off);
    }
    const float inv = 1.f / zsum;

    if (lane < 8) {
        if constexpr (OUTBF) {
            bf16x8 w0, w1;
            #pragma unroll
            for (int q = 0; q < 8; ++q) {
                ((unsigned short*)&w0)[q] = f2bf(acc[q] * inv);
                ((unsigned short*)&w1)[q] = f2bf(acc[q + 8] * inv);
            }
            *(bf16x8*)(obf + (size_t)node * F + lr * 16) = w0;
            *(bf16x8*)(obf + (size_t)node * F + lr * 16 + 8) = w1;
        } else {
            float o[16];
            #pragma unroll
            for (int q = 0; q < 16; ++q)
                o[q] = acc[q] * inv + bias[lr * 16 + q];
            float* op = outf + (size_t)node * F + lr * 16;
            *(float4*)op = {o[0], o[1], o[2], o[3]};
            *(float4*)(op + 4) = {o[4], o[5], o[6], o[7]};
            *(float4*)(op + 8) = {o[8], o[9], o[10], o[11]};
            *(float4*)(op + 12) = {o[12], o[13], o[14], o[15]};
        }
    }
}

extern "C" void kernel_launch(void* const* d_in, const int* in_sizes, int n_in,
                              void* d_out, int out_size, void* d_ws, size_t ws_size,
                              hipStream_t stream) {
    const float* x      = (const float*)d_in[0];
    const int*   eidx   = (const int*)d_in[1];
    const float* W1     = (const float*)d_in[2];
    const float* a_src1 = (const float*)d_in[3];
    const float* a_dst1 = (const float*)d_in[4];
    const float* b1     = (const float*)d_in[5];
    const float* W2     = (const float*)d_in[6];
    const float* a_src2 = (const float*)d_in[7];
    const float* a_dst2 = (const float*)d_in[8];
    const float* b2     = (const float*)d_in[9];

    const int N = in_sizes[0] / 128;   // 50000
    const int E = in_sizes[1] / 2;     // 800000
    const int F_IN = 128, H = 256, F_OUT = 128;
    const int EA = E + N;

    const int* srcE = eidx;
    const int* dstE = eidx + E;

    // ---- workspace layout (~74 MB) ----
    unsigned short* xbf    = (unsigned short*)d_ws;                 // N*128 bf16
    unsigned short* aggx   = xbf + (size_t)N * F_IN;                // N*128 bf16
    unsigned short* g1     = aggx + (size_t)N * F_IN;               // N*256 bf16
    unsigned short* h2bf   = g1 + (size_t)N * H;                    // N*128 bf16
    float*          sbuf   = (float*)(h2bf + (size_t)N * F_OUT);    // N
    float*          dbuf   = sbuf + N;                              // N
    float*          w_s1   = dbuf + N;                              // 128
    float*          w_d1   = w_s1 + F_IN;                           // 128
    unsigned short* w1T    = (unsigned short*)(w_d1 + F_IN);        // 256*128
    unsigned short* w2T    = w1T + 32768;                           // 128*256
    int*            rowptr = (int*)(w2T + 32768);                   // N+1
    int*            cnt    = rowptr + (N + 1);                      // NREP*N
    int*            part   = cnt + NREP * N;                        // 32
    int*            ssrc   = part + 32;                             // E+N
    int*            rank   = ssrc + EA;                             // E+N

    float* out = (float*)d_out;

    const int nseg = (N + SCAN_SEG - 1) / SCAN_SEG;   // 25
    const int xblocks = (N * 64 + 255) / 256;         // 12500

    // 1) weight prep + cnt zero
    wprep_k<<<288, 256, 0, stream>>>(W1, W2, a_src1, a_dst1, w1T, w2T,
                                     w_s1, w_d1, cnt, N);
    // 2) rank (atomics) + xprep (BW) merged
    rank_xprep_k<<<RANK_BLOCKS + xblocks, 256, 0, stream>>>(
        dstE, cnt, rank, x, w_s1, w_d1, xbf, sbuf, dbuf, E, N);
    // 3) scan part sums
    scan_part_k<<<nseg, 256, 0, stream>>>(cnt, part, N);
    // 4) scan write (in-block part prefix, rowptr, replica bases)
    scan_write_k<<<nseg, 256, 0, stream>>>(cnt, rowptr, part, nseg, N);
    // 5) place
    place_k<<<RANK_BLOCKS, 256, 0, stream>>>(srcE, dstE, cnt, rank, ssrc, E, N);

    // 6) layer-1 gather
    {
        int nb = (N + 3) / 4;
        node_gather_k<true><<<nb, 256, 0, stream>>>(
            rowptr, ssrc, sbuf, dbuf, xbf, nullptr, aggx, nullptr, N);
    }
    // 7) GEMM1 (relu+bias epilogue)
    {
        dim3 gg((N + 127) / 128, H / 128);
        gemm_bf16<128, 256, 1><<<gg, 256, 0, stream>>>(
            aggx, w1T, g1, b1, nullptr, nullptr, nullptr, nullptr, N);
    }
    // 8) GEMM2 (+ in-epilogue layer-2 rowdots)
    {
        dim3 gg((N + 127) / 128, 1);
        gemm_bf16<256, 128, 2><<<gg, 256, 0, stream>>>(
            g1, w2T, h2bf, nullptr, a_src2, a_dst2, sbuf, dbuf, N);
    }
    // 9) layer-2 gather (final output)
    {
        int nb = (N + 3) / 4;
        node_gather_k<false><<<nb, 256, 0, stream>>>(
            rowptr, ssrc, sbuf, dbuf, h2bf, b2, nullptr, out, N);
    }
}

// Round 17
// 155.502 us; speedup vs baseline: 3.6170x; 1.1472x over previous
//
#include <hip/hip_runtime.h>
#include <hip/hip_bf16.h>

// ---------------------------------------------------------------------------
// GAT encoder, 2 layers. Round 17: round-16 back-end + ATOMIC-FREE CSR build.
// rank (850K device atomics @ ~20/ns ceiling = 45us) replaced by a 2-level
// counting sort on dst>>5: LDS histograms -> column scan -> LDS-rank scatter
// -> per-bucket LDS counting sort (writes ssrc + rowptr). 10 dispatches.
// ---------------------------------------------------------------------------

#define NEG_SLOPE 0.2f
#define NB 104          // hist/scatter blocks
#define EPB 8192        // edges per block; NB*EPB = 851968 >= E+N
#define NBUCKET 1568    // buckets of 32 dsts (49999>>5 = 1562)
#define BSH 5

typedef __attribute__((ext_vector_type(8))) short bf16x8;
typedef __attribute__((ext_vector_type(4))) float f32x4;

__device__ __forceinline__ unsigned short f2bf(float v) {
    __hip_bfloat16 b = __float2bfloat16(v);
    return *reinterpret_cast<unsigned short*>(&b);
}
__device__ __forceinline__ float bf2f(unsigned short u) {
    __hip_bfloat16 b = *reinterpret_cast<__hip_bfloat16*>(&u);
    return __bfloat162float(b);
}

// ---- weight prep: W1T, W2T (f32->bf16), W1 projection dots ----
__global__ __launch_bounds__(256) void wprep_k(
    const float* __restrict__ W1, const float* __restrict__ W2,
    const float* __restrict__ a_src1, const float* __restrict__ a_dst1,
    unsigned short* __restrict__ w1T, unsigned short* __restrict__ w2T,
    float* __restrict__ w_s1, float* __restrict__ w_d1) {
    const int b = blockIdx.x;
    if (b < 128) {
        int i = b * 256 + threadIdx.x;
        int k = i >> 8, n = i & 255;
        w1T[n * 128 + k] = f2bf(W1[i]);
    } else if (b < 256) {
        int j = (b - 128) * 256 + threadIdx.x;
        int k = j >> 7, n = j & 127;
        w2T[n * 256 + k] = f2bf(W2[j]);
    } else {
        int w = ((b - 256) * 256 + threadIdx.x) >> 6;  // 0..127
        int lane = threadIdx.x & 63;
        const float* row = W1 + (size_t)w * 256;
        float ss = 0.f, dd = 0.f;
        #pragma unroll
        for (int f = lane; f < 256; f += 64) {
            float v = row[f];
            ss += v * a_src1[f];
            dd += v * a_dst1[f];
        }
        #pragma unroll
        for (int off = 32; off; off >>= 1) {
            ss += __shfl_down(ss, off);
            dd += __shfl_down(dd, off);
        }
        if (lane == 0) { w_s1[w] = ss; w_d1[w] = dd; }
    }
}

// ---- F: blocks [0,NB): LDS bucket histogram; blocks [NB,...): xprep ----
__global__ __launch_bounds__(256) void hist_xprep_k(
    const int* __restrict__ dstE, const float* __restrict__ x,
    const float* __restrict__ va, const float* __restrict__ vb,
    int* __restrict__ histG, unsigned short* __restrict__ xbf,
    float* __restrict__ s, float* __restrict__ d, int E, int N) {
    const int b = blockIdx.x;
    if (b < NB) {
        __shared__ int h[NBUCKET];
        for (int i = threadIdx.x; i < NBUCKET; i += 256) h[i] = 0;
        __syncthreads();
        const int base = b * EPB;
        const int total = E + N;
        #pragma unroll
        for (int q = 0; q < EPB / 256; ++q) {
            int i = base + q * 256 + threadIdx.x;
            if (i < total) {
                int di = (i < E) ? dstE[i] : i - E;
                atomicAdd(&h[di >> BSH], 1);
            }
        }
        __syncthreads();
        for (int i = threadIdx.x; i < NBUCKET; i += 256)
            histG[b * NBUCKET + i] = h[i];
    } else {
        int w = (((b - NB) * 256) + threadIdx.x) >> 6;
        int lane = threadIdx.x & 63;
        if (w >= N) return;
        float2 v = *(const float2*)(x + (size_t)w * 128 + lane * 2);
        ushort2 u;
        u.x = f2bf(v.x);
        u.y = f2bf(v.y);
        *(ushort2*)(xbf + (size_t)w * 128 + lane * 2) = u;
        float ss = v.x * va[lane * 2] + v.y * va[lane * 2 + 1];
        float dd = v.x * vb[lane * 2] + v.y * vb[lane * 2 + 1];
        #pragma unroll
        for (int off = 32; off; off >>= 1) {
            ss += __shfl_down(ss, off);
            dd += __shfl_down(dd, off);
        }
        if (lane == 0) { s[w] = ss; d[w] = dd; }
    }
}

// ---- S: per-bucket column scan. histG[blk][bkt] <- prefix over blk;
//      colSum[bkt] = total. One wave per bucket. ----
__global__ __launch_bounds__(256) void colscan_k(
    int* __restrict__ histG, int* __restrict__ colSum) {
    const int bkt = blockIdx.x * 4 + (threadIdx.x >> 6);
    const int l = threadIdx.x & 63;
    int carry = 0;
    #pragma unroll
    for (int c = 0; c < 2; ++c) {
        int blk = c * 64 + l;
        int v = (blk < NB) ? histG[blk * NBUCKET + bkt] : 0;
        int incl = v;
        #pragma unroll
        for (int off = 1; off < 64; off <<= 1) {
            int t = __shfl_up(incl, off);
            if (l >= off) incl += t;
        }
        if (blk < NB) histG[blk * NBUCKET + bkt] = carry + (incl - v);
        carry += __shfl(incl, 63);
    }
    if (l == 0) colSum[bkt] = carry;
}

// ---- S2: single-block scan over colSum -> bucketBase[0..NBUCKET] ----
__global__ __launch_bounds__(256) void bucketbase_k(
    const int* __restrict__ colSum, int* __restrict__ bb, int total) {
    __shared__ int wsum[4];
    const int tid = threadIdx.x;
    const int lane = tid & 63, wv = tid >> 6;
    const int base = tid * 7;   // 256*7 = 1792 >= NBUCKET
    int loc[7];
    int s = 0;
    #pragma unroll
    for (int q = 0; q < 7; ++q) {
        int idx = base + q;
        int c = (idx < NBUCKET) ? colSum[idx] : 0;
        loc[q] = s;
        s += c;
    }
    int incl = s;
    #pragma unroll
    for (int off = 1; off < 64; off <<= 1) {
        int t = __shfl_up(incl, off);
        if (lane >= off) incl += t;
    }
    if (lane == 63) wsum[wv] = incl;
    __syncthreads();
    if (tid == 0) {
        int r = 0;
        #pragma unroll
        for (int i = 0; i < 4; ++i) { int c = wsum[i]; wsum[i] = r; r += c; }
    }
    __syncthreads();
    const int b0 = wsum[wv] + (incl - s);
    #pragma unroll
    for (int q = 0; q < 7; ++q) {
        int idx = base + q;
        if (idx < NBUCKET) bb[idx] = b0 + loc[q];
    }
    if (tid == 0) bb[NBUCKET] = total;
}

// ---- B: scatter packed (dst<<16|src) into bucket-grouped order.
//      pos = bb[bkt] + histG[blk][bkt] + LDS rank. No global atomics. ----
__global__ __launch_bounds__(256) void bscatter_k(
    const int* __restrict__ srcE, const int* __restrict__ dstE,
    const int* __restrict__ histG, const int* __restrict__ bb,
    unsigned* __restrict__ packed, int E, int N) {
    __shared__ int cur[NBUCKET];
    for (int i = threadIdx.x; i < NBUCKET; i += 256) cur[i] = 0;
    __syncthreads();
    const int b = blockIdx.x;
    const int base = b * EPB;
    const int total = E + N;
    #pragma unroll
    for (int q = 0; q < EPB / 256; ++q) {
        int i = base + q * 256 + threadIdx.x;
        if (i < total) {
            int di, si;
            if (i < E) { di = dstE[i]; si = srcE[i]; }
            else       { di = si = i - E; }
            int bk = di >> BSH;
            int r = atomicAdd(&cur[bk], 1);
            packed[bb[bk] + histG[b * NBUCKET + bk] + r] =
                ((unsigned)di << 16) | (unsigned)si;
        }
    }
}

// ---- C: per-bucket LDS counting sort over its 32 dsts; writes ssrc+rowptr ----
__global__ __launch_bounds__(256) void bsort_k(
    const unsigned* __restrict__ packed, const int* __restrict__ bb,
    int* __restrict__ ssrc, int* __restrict__ rowptr, int N) {
    __shared__ unsigned arr[2048];
    __shared__ int cnt[32], pf[32], cur[32];
    const int b = blockIdx.x;
    const int beg = bb[b], end = bb[b + 1];
    const int L = end - beg;   // mean 544, sigma ~23; 2048 cap = 66 sigma
    if (threadIdx.x < 32) cnt[threadIdx.x] = 0;
    __syncthreads();
    for (int t = threadIdx.x; t < L; t += 256) {
        unsigned e = packed[beg + t];
        arr[t] = e;
        atomicAdd(&cnt[(e >> 16) & 31], 1);
    }
    __syncthreads();
    if (threadIdx.x == 0) {
        int r = 0;
        #pragma unroll
        for (int j = 0; j < 32; ++j) { pf[j] = r; cur[j] = r; r += cnt[j]; }
    }
    __syncthreads();
    if (threadIdx.x < 32) {
        int dd = b * 32 + threadIdx.x;
        if (dd < N) rowptr[dd] = beg + pf[threadIdx.x];
    }
    for (int t = threadIdx.x; t < L; t += 256) {
        unsigned e = arr[t];
        int r = atomicAdd(&cur[(e >> 16) & 31], 1);
        ssrc[beg + r] = (int)(e & 0xffffu);
    }
    if (b == 0 && threadIdx.x == 0) rowptr[N] = bb[NBUCKET];
}

// ---- bf16 MFMA GEMM, BM=128 BN=128 BK=32 (unchanged from round 16) ----
template <int K, int NN, int EPI>
__global__ __launch_bounds__(256) void gemm_bf16(
    const unsigned short* __restrict__ A, const unsigned short* __restrict__ BT,
    unsigned short* __restrict__ C, const float* __restrict__ bias,
    const float* __restrict__ va, const float* __restrict__ vb,
    float* __restrict__ sOut, float* __restrict__ dOut, int M) {
    constexpr int BK = 32, PAD = 8;
    __shared__ short As[128][BK + PAD];
    __shared__ short Bs[128][BK + PAD];
    const int tid = threadIdx.x;
    const int wv = tid >> 6;
    const int ln = tid & 63;
    const int row0 = blockIdx.x * 128;
    const int col0 = blockIdx.y * 128;

    f32x4 acc[2][8];
    #pragma unroll
    for (int m = 0; m < 2; ++m)
        #pragma unroll
        for (int n = 0; n < 8; ++n) acc[m][n] = {0.f, 0.f, 0.f, 0.f};

    const int l15 = ln & 15;
    const int kg = (ln >> 4) * 8;

    for (int k0 = 0; k0 < K; k0 += BK) {
        #pragma unroll
        for (int t = 0; t < 2; ++t) {
            int v = tid + t * 256;
            int r = v >> 2;
            int kc = (v & 3) * 8;
            bf16x8 val = {0, 0, 0, 0, 0, 0, 0, 0};
            int gr = row0 + r;
            if (gr < M)
                val = *(const bf16x8*)(A + (size_t)gr * K + k0 + kc);
            *(bf16x8*)(&As[r][kc]) = val;
        }
        #pragma unroll
        for (int t = 0; t < 2; ++t) {
            int v = tid + t * 256;
            int c = v >> 2;
            int kc = (v & 3) * 8;
            *(bf16x8*)(&Bs[c][kc]) =
                *(const bf16x8*)(BT + (size_t)(col0 + c) * K + k0 + kc);
        }
        __syncthreads();

        bf16x8 ah[2], bh[8];
        #pragma unroll
        for (int m = 0; m < 2; ++m)
            ah[m] = *(const bf16x8*)&As[wv * 32 + m * 16 + l15][kg];
        #pragma unroll
        for (int n = 0; n < 8; ++n)
            bh[n] = *(const bf16x8*)&Bs[n * 16 + l15][kg];
        #pragma unroll
        for (int m = 0; m < 2; ++m)
            #pragma unroll
            for (int n = 0; n < 8; ++n)
                acc[m][n] = __builtin_amdgcn_mfma_f32_16x16x32_bf16(
                    ah[m], bh[n], acc[m][n], 0, 0, 0);
        __syncthreads();
    }

    const int crow = (ln >> 4) * 4;
    #pragma unroll
    for (int m = 0; m < 2; ++m) {
        #pragma unroll
        for (int q = 0; q < 4; ++q) {
            int gr = row0 + wv * 32 + m * 16 + crow + q;
            if (gr >= M) continue;
            if constexpr (EPI == 1) {
                #pragma unroll
                for (int n = 0; n < 8; ++n) {
                    int gc = col0 + n * 16 + l15;
                    float v = acc[m][n][q] + bias[gc];
                    v = fmaxf(v, 0.f);
                    C[(size_t)gr * NN + gc] = f2bf(v);
                }
            } else {
                float sp = 0.f, dp = 0.f;
                #pragma unroll
                for (int n = 0; n < 8; ++n) {
                    int gc = n * 16 + l15;
                    float v = acc[m][n][q];
                    C[(size_t)gr * NN + gc] = f2bf(v);
                    sp += v * va[gc];
                    dp += v * vb[gc];
                }
                #pragma unroll
                for (int off = 1; off < 16; off <<= 1) {
                    sp += __shfl_xor(sp, off);
                    dp += __shfl_xor(dp, off);
                }
                if (l15 == 0) { sOut[gr] = sp; dOut[gr] = dp; }
            }
        }
    }
}

// ---- fused softmax + weighted gather (unchanged from round 16) ----
template <bool OUTBF>
__global__ __launch_bounds__(256) void node_gather_k(
    const int* __restrict__ rowptr, const int* __restrict__ ssrc,
    const float* __restrict__ s, const float* __restrict__ d,
    const unsigned short* __restrict__ hsrc, const float* __restrict__ bias,
    unsigned short* __restrict__ obf, float* __restrict__ outf, int N) {
    constexpr int F = 128, G = 8;
    const int node = blockIdx.x * 4 + (threadIdx.x >> 6);
    const int lane = threadIdx.x & 63;
    if (node >= N) return;
    const int beg = rowptr[node];
    const int end = rowptr[node + 1];
    const float dn = d[node];
    const int grp = lane >> 3;
    const int lr = lane & 7;

    float acc[16] = {};
    float zsum = 0.f;
    int j = beg + grp;
    for (; j + G < end; j += 2 * G) {
        int sj0 = ssrc[j];
        int sj1 = ssrc[j + G];
        float e0 = s[sj0] + dn;
        float e1 = s[sj1] + dn;
        const unsigned short* r0 = hsrc + (size_t)sj0 * F + lr * 16;
        const unsigned short* r1 = hsrc + (size_t)sj1 * F + lr * 16;
        bf16x8 v0a = *(const bf16x8*)r0;
        bf16x8 v0b = *(const bf16x8*)(r0 + 8);
        bf16x8 v1a = *(const bf16x8*)r1;
        bf16x8 v1b = *(const bf16x8*)(r1 + 8);
        e0 = (e0 > 0.f) ? e0 : NEG_SLOPE * e0;
        e1 = (e1 > 0.f) ? e1 : NEG_SLOPE * e1;
        float x0 = __expf(e0);
        float x1 = __expf(e1);
        zsum += x0 + x1;
        #pragma unroll
        for (int q = 0; q < 8; ++q) {
            acc[q]     += x0 * bf2f(((unsigned short*)&v0a)[q]);
            acc[q + 8] += x0 * bf2f(((unsigned short*)&v0b)[q]);
            acc[q]     += x1 * bf2f(((unsigned short*)&v1a)[q]);
            acc[q + 8] += x1 * bf2f(((unsigned short*)&v1b)[q]);
        }
    }
    if (j < end) {
        int sj = ssrc[j];
        float e = s[sj] + dn;
        e = (e > 0.f) ? e : NEG_SLOPE * e;
        float exj = __expf(e);
        zsum += exj;
        const unsigned short* r0 = hsrc + (size_t)sj * F + lr * 16;
        bf16x8 va_ = *(const bf16x8*)r0;
        bf16x8 vb_ = *(const bf16x8*)(r0 + 8);
        #pragma unroll
        for (int q = 0; q < 8; ++q) {
            acc[q]     += exj * bf2f(((unsigned short*)&va_)[q]);
            acc[q + 8] += exj * bf2f(((unsigned short*)&vb_)[q]);
        }
    }
    #pragma unroll
    for (int off = 8; off < 64; off <<= 1) {
        zsum += __shfl_xor(zsum, off);
        #pragma unroll
        for (int q = 0; q < 16; ++q) acc[q] += __shfl_xor(acc[q], off);
    }
    const float inv = 1.f / zsum;

    if (lane < 8) {
        if constexpr (OUTBF) {
            bf16x8 w0, w1;
            #pragma unroll
            for (int q = 0; q < 8; ++q) {
                ((unsigned short*)&w0)[q] = f2bf(acc[q] * inv);
                ((unsigned short*)&w1)[q] = f2bf(acc[q + 8] * inv);
            }
            *(bf16x8*)(obf + (size_t)node * F + lr * 16) = w0;
            *(bf16x8*)(obf + (size_t)node * F + lr * 16 + 8) = w1;
        } else {
            float o[16];
            #pragma unroll
            for (int q = 0; q < 16; ++q)
                o[q] = acc[q] * inv + bias[lr * 16 + q];
            float* op = outf + (size_t)node * F + lr * 16;
            *(float4*)op = {o[0], o[1], o[2], o[3]};
            *(float4*)(op + 4) = {o[4], o[5], o[6], o[7]};
            *(float4*)(op + 8) = {o[8], o[9], o[10], o[11]};
            *(float4*)(op + 12) = {o[12], o[13], o[14], o[15]};
        }
    }
}

extern "C" void kernel_launch(void* const* d_in, const int* in_sizes, int n_in,
                              void* d_out, int out_size, void* d_ws, size_t ws_size,
                              hipStream_t stream) {
    const float* x      = (const float*)d_in[0];
    const int*   eidx   = (const int*)d_in[1];
    const float* W1     = (const float*)d_in[2];
    const float* a_src1 = (const float*)d_in[3];
    const float* a_dst1 = (const float*)d_in[4];
    const float* b1     = (const float*)d_in[5];
    const float* W2     = (const float*)d_in[6];
    const float* a_src2 = (const float*)d_in[7];
    const float* a_dst2 = (const float*)d_in[8];
    const float* b2     = (const float*)d_in[9];

    const int N = in_sizes[0] / 128;   // 50000
    const int E = in_sizes[1] / 2;     // 800000
    const int F_IN = 128, H = 256, F_OUT = 128;
    const int EA = E + N;

    const int* srcE = eidx;
    const int* dstE = eidx + E;

    // ---- workspace layout ----
    unsigned short* xbf    = (unsigned short*)d_ws;                 // N*128 bf16
    unsigned short* aggx   = xbf + (size_t)N * F_IN;                // N*128 bf16
    unsigned short* g1     = aggx + (size_t)N * F_IN;               // N*256 bf16
    unsigned short* h2bf   = g1 + (size_t)N * H;                    // N*128 bf16
    float*          sbuf   = (float*)(h2bf + (size_t)N * F_OUT);    // N
    float*          dbuf   = sbuf + N;                              // N
    float*          w_s1   = dbuf + N;                              // 128
    float*          w_d1   = w_s1 + F_IN;                           // 128
    unsigned short* w1T    = (unsigned short*)(w_d1 + F_IN);        // 256*128
    unsigned short* w2T    = w1T + 32768;                           // 128*256
    int*            rowptr = (int*)(w2T + 32768);                   // N+1
    int*            histG  = rowptr + (N + 1);                      // NB*NBUCKET
    int*            colSum = histG + NB * NBUCKET;                  // NBUCKET
    int*            bb     = colSum + NBUCKET;                      // NBUCKET+1
    int*            ssrc   = bb + NBUCKET + 1;                      // E+N
    unsigned*       packed = (unsigned*)(ssrc + EA);                // E+N

    float* out = (float*)d_out;
    const int xblocks = (N * 64 + 255) / 256;   // 12500

    // 1) weight prep
    wprep_k<<<288, 256, 0, stream>>>(W1, W2, a_src1, a_dst1, w1T, w2T, w_s1, w_d1);
    // 2) bucket histograms + xprep
    hist_xprep_k<<<NB + xblocks, 256, 0, stream>>>(
        dstE, x, w_s1, w_d1, histG, xbf, sbuf, dbuf, E, N);
    // 3) per-bucket column scan (per-block bases + totals)
    colscan_k<<<NBUCKET / 4, 256, 0, stream>>>(histG, colSum);
    // 4) bucket base prefix
    bucketbase_k<<<1, 256, 0, stream>>>(colSum, bb, EA);
    // 5) scatter into bucket-grouped order (LDS ranks, no global atomics)
    bscatter_k<<<NB, 256, 0, stream>>>(srcE, dstE, histG, bb, packed, E, N);
    // 6) per-bucket counting sort -> ssrc + rowptr
    bsort_k<<<NBUCKET, 256, 0, stream>>>(packed, bb, ssrc, rowptr, N);

    // 7) layer-1 gather
    {
        int nb = (N + 3) / 4;
        node_gather_k<true><<<nb, 256, 0, stream>>>(
            rowptr, ssrc, sbuf, dbuf, xbf, nullptr, aggx, nullptr, N);
    }
    // 8) GEMM1 (relu+bias epilogue)
    {
        dim3 gg((N + 127) / 128, H / 128);
        gemm_bf16<128, 256, 1><<<gg, 256, 0, stream>>>(
            aggx, w1T, g1, b1, nullptr, nullptr, nullptr, nullptr, N);
    }
    // 9) GEMM2 (+ in-epilogue layer-2 rowdots)
    {
        dim3 gg((N + 127) / 128, 1);
        gemm_bf16<256, 128, 2><<<gg, 256, 0, stream>>>(
            g1, w2T, h2bf, nullptr, a_src2, a_dst2, sbuf, dbuf, N);
    }
    // 10) layer-2 gather (final output)
    {
        int nb = (N + 3) / 4;
        node_gather_k<false><<<nb, 256, 0, stream>>>(
            rowptr, ssrc, sbuf, dbuf, h2bf, b2, nullptr, out, N);
    }
}

// Round 18
// 153.916 us; speedup vs baseline: 3.6543x; 1.0103x over previous
//
#include <hip/hip_runtime.h>
#include <hip/hip_bf16.h>

// ---------------------------------------------------------------------------
// GAT encoder, 2 layers. Round 18: round-17 pipeline squeezed to 8 dispatches:
//  K1 hist+wprep | K2 colscan+xprep | K3 bscatter(inline bb-scan) |
//  K4 bsort(inline base-reduce) | gather1 | gemm1 | gemm2 | gather2
// ---------------------------------------------------------------------------

#define NEG_SLOPE 0.2f
#define NB 104          // hist/scatter blocks
#define EPB 8192        // edges per block; NB*EPB = 851968 >= E+N
#define NBUCKET 1568    // buckets of 32 dsts
#define BSH 5

typedef __attribute__((ext_vector_type(8))) short bf16x8;
typedef __attribute__((ext_vector_type(4))) float f32x4;

__device__ __forceinline__ unsigned short f2bf(float v) {
    __hip_bfloat16 b = __float2bfloat16(v);
    return *reinterpret_cast<unsigned short*>(&b);
}
__device__ __forceinline__ float bf2f(unsigned short u) {
    __hip_bfloat16 b = *reinterpret_cast<__hip_bfloat16*>(&u);
    return __bfloat162float(b);
}

// ---- K1: blocks [0,NB): LDS bucket histogram. [NB,NB+256): W transposes.
//      [NB+256,NB+288): W1 projection dots. ----
__global__ __launch_bounds__(256) void hist_wprep_k(
    const int* __restrict__ dstE, const float* __restrict__ W1,
    const float* __restrict__ W2, const float* __restrict__ a_src1,
    const float* __restrict__ a_dst1, int* __restrict__ histG,
    unsigned short* __restrict__ w1T, unsigned short* __restrict__ w2T,
    float* __restrict__ w_s1, float* __restrict__ w_d1, int E, int N) {
    const int b = blockIdx.x;
    if (b < NB) {
        __shared__ int h[NBUCKET];
        for (int i = threadIdx.x; i < NBUCKET; i += 256) h[i] = 0;
        __syncthreads();
        const int base = b * EPB;
        const int total = E + N;
        #pragma unroll
        for (int q = 0; q < EPB / 256; ++q) {
            int i = base + q * 256 + threadIdx.x;
            if (i < total) {
                int di = (i < E) ? dstE[i] : i - E;
                atomicAdd(&h[di >> BSH], 1);
            }
        }
        __syncthreads();
        for (int i = threadIdx.x; i < NBUCKET; i += 256)
            histG[b * NBUCKET + i] = h[i];
    } else if (b < NB + 128) {           // W1[128][256] -> w1T[256][128]
        int i = (b - NB) * 256 + threadIdx.x;
        int k = i >> 8, n = i & 255;
        w1T[n * 128 + k] = f2bf(W1[i]);
    } else if (b < NB + 256) {           // W2[256][128] -> w2T[128][256]
        int j = (b - NB - 128) * 256 + threadIdx.x;
        int k = j >> 7, n = j & 127;
        w2T[n * 256 + k] = f2bf(W2[j]);
    } else {                             // projection dots
        int w = ((b - NB - 256) * 256 + threadIdx.x) >> 6;  // 0..127
        int lane = threadIdx.x & 63;
        const float* row = W1 + (size_t)w * 256;
        float ss = 0.f, dd = 0.f;
        #pragma unroll
        for (int f = lane; f < 256; f += 64) {
            float v = row[f];
            ss += v * a_src1[f];
            dd += v * a_dst1[f];
        }
        #pragma unroll
        for (int off = 32; off; off >>= 1) {
            ss += __shfl_down(ss, off);
            dd += __shfl_down(dd, off);
        }
        if (lane == 0) { w_s1[w] = ss; w_d1[w] = dd; }
    }
}

// ---- K2: blocks [0, NBUCKET/4): per-bucket column scan (histG in place,
//      colSum out). blocks after: xprep (x->bf16 + s/d dots). ----
__global__ __launch_bounds__(256) void colscan_xprep_k(
    int* __restrict__ histG, int* __restrict__ colSum,
    const float* __restrict__ x, const float* __restrict__ va,
    const float* __restrict__ vb, unsigned short* __restrict__ xbf,
    float* __restrict__ s, float* __restrict__ d, int N) {
    const int b = blockIdx.x;
    constexpr int CSB = NBUCKET / 4;   // 392
    if (b < CSB) {
        const int bkt = b * 4 + (threadIdx.x >> 6);
        const int l = threadIdx.x & 63;
        int carry = 0;
        #pragma unroll
        for (int c = 0; c < 2; ++c) {
            int blk = c * 64 + l;
            int v = (blk < NB) ? histG[blk * NBUCKET + bkt] : 0;
            int incl = v;
            #pragma unroll
            for (int off = 1; off < 64; off <<= 1) {
                int t = __shfl_up(incl, off);
                if (l >= off) incl += t;
            }
            if (blk < NB) histG[blk * NBUCKET + bkt] = carry + (incl - v);
            carry += __shfl(incl, 63);
        }
        if (l == 0) colSum[bkt] = carry;
    } else {
        int w = (((b - CSB) * 256) + threadIdx.x) >> 6;
        int lane = threadIdx.x & 63;
        if (w >= N) return;
        float2 v = *(const float2*)(x + (size_t)w * 128 + lane * 2);
        ushort2 u;
        u.x = f2bf(v.x);
        u.y = f2bf(v.y);
        *(ushort2*)(xbf + (size_t)w * 128 + lane * 2) = u;
        float ss = v.x * va[lane * 2] + v.y * va[lane * 2 + 1];
        float dd = v.x * vb[lane * 2] + v.y * vb[lane * 2 + 1];
        #pragma unroll
        for (int off = 32; off; off >>= 1) {
            ss += __shfl_down(ss, off);
            dd += __shfl_down(dd, off);
        }
        if (lane == 0) { s[w] = ss; d[w] = dd; }
    }
}

// ---- K3: scatter packed (dst<<16|src) into bucket-grouped order.
//      Bucket bases computed in-LDS (exclusive scan of colSum). ----
__global__ __launch_bounds__(256) void bscatter_k(
    const int* __restrict__ srcE, const int* __restrict__ dstE,
    const int* __restrict__ histG, const int* __restrict__ colSum,
    unsigned* __restrict__ packed, int E, int N) {
    __shared__ int bb_s[NBUCKET];
    __shared__ int cur[NBUCKET];
    __shared__ int wsum[4];
    const int tid = threadIdx.x;
    // exclusive scan of colSum -> bb_s
    {
        const int lane = tid & 63, wv = tid >> 6;
        const int base = tid * 7;   // 256*7 >= NBUCKET
        int loc[7];
        int ssum = 0;
        #pragma unroll
        for (int q = 0; q < 7; ++q) {
            int idx = base + q;
            int c = (idx < NBUCKET) ? colSum[idx] : 0;
            loc[q] = ssum;
            ssum += c;
        }
        int incl = ssum;
        #pragma unroll
        for (int off = 1; off < 64; off <<= 1) {
            int t = __shfl_up(incl, off);
            if (lane >= off) incl += t;
        }
        if (lane == 63) wsum[wv] = incl;
        __syncthreads();
        if (tid == 0) {
            int r = 0;
            #pragma unroll
            for (int i = 0; i < 4; ++i) { int c = wsum[i]; wsum[i] = r; r += c; }
        }
        __syncthreads();
        const int b0 = wsum[wv] + (incl - ssum);
        #pragma unroll
        for (int q = 0; q < 7; ++q) {
            int idx = base + q;
            if (idx < NBUCKET) bb_s[idx] = b0 + loc[q];
        }
    }
    for (int i = tid; i < NBUCKET; i += 256) cur[i] = 0;
    __syncthreads();
    const int b = blockIdx.x;
    const int base = b * EPB;
    const int total = E + N;
    #pragma unroll
    for (int q = 0; q < EPB / 256; ++q) {
        int i = base + q * 256 + tid;
        if (i < total) {
            int di, si;
            if (i < E) { di = dstE[i]; si = srcE[i]; }
            else       { di = si = i - E; }
            int bk = di >> BSH;
            int r = atomicAdd(&cur[bk], 1);
            packed[bb_s[bk] + histG[b * NBUCKET + bk] + r] =
                ((unsigned)di << 16) | (unsigned)si;
        }
    }
}

// ---- K4: per-bucket LDS counting sort; beg via block reduce of colSum. ----
__global__ __launch_bounds__(256) void bsort_k(
    const unsigned* __restrict__ packed, const int* __restrict__ colSum,
    int* __restrict__ ssrc, int* __restrict__ rowptr, int EA, int N) {
    __shared__ unsigned arr[2048];
    __shared__ int cnt[32], pf[32], cur[32];
    __shared__ int red[4];
    __shared__ int beg_s;
    const int b = blockIdx.x;
    const int tid = threadIdx.x;
    // beg = sum(colSum[0..b))
    {
        int part = 0;
        for (int i = tid; i < b; i += 256) part += colSum[i];
        #pragma unroll
        for (int off = 32; off; off >>= 1) part += __shfl_down(part, off);
        if ((tid & 63) == 0) red[tid >> 6] = part;
        __syncthreads();
        if (tid == 0) beg_s = red[0] + red[1] + red[2] + red[3];
    }
    if (tid < 32) cnt[tid] = 0;
    __syncthreads();
    const int beg = beg_s;
    const int L = colSum[b];
    for (int t = tid; t < L; t += 256) {
        unsigned e = packed[beg + t];
        arr[t] = e;
        atomicAdd(&cnt[(e >> 16) & 31], 1);
    }
    __syncthreads();
    if (tid == 0) {
        int r = 0;
        #pragma unroll
        for (int j = 0; j < 32; ++j) { pf[j] = r; cur[j] = r; r += cnt[j]; }
    }
    __syncthreads();
    if (tid < 32) {
        int dd = b * 32 + tid;
        if (dd < N) rowptr[dd] = beg + pf[tid];
    }
    for (int t = tid; t < L; t += 256) {
        unsigned e = arr[t];
        int r = atomicAdd(&cur[(e >> 16) & 31], 1);
        ssrc[beg + r] = (int)(e & 0xffffu);
    }
    if (b == 0 && tid == 0) rowptr[N] = EA;
}

// ---- bf16 MFMA GEMM, BM=128 BN=128 BK=32 (unchanged) ----
template <int K, int NN, int EPI>
__global__ __launch_bounds__(256) void gemm_bf16(
    const unsigned short* __restrict__ A, const unsigned short* __restrict__ BT,
    unsigned short* __restrict__ C, const float* __restrict__ bias,
    const float* __restrict__ va, const float* __restrict__ vb,
    float* __restrict__ sOut, float* __restrict__ dOut, int M) {
    constexpr int BK = 32, PAD = 8;
    __shared__ short As[128][BK + PAD];
    __shared__ short Bs[128][BK + PAD];
    const int tid = threadIdx.x;
    const int wv = tid >> 6;
    const int ln = tid & 63;
    const int row0 = blockIdx.x * 128;
    const int col0 = blockIdx.y * 128;

    f32x4 acc[2][8];
    #pragma unroll
    for (int m = 0; m < 2; ++m)
        #pragma unroll
        for (int n = 0; n < 8; ++n) acc[m][n] = {0.f, 0.f, 0.f, 0.f};

    const int l15 = ln & 15;
    const int kg = (ln >> 4) * 8;

    for (int k0 = 0; k0 < K; k0 += BK) {
        #pragma unroll
        for (int t = 0; t < 2; ++t) {
            int v = tid + t * 256;
            int r = v >> 2;
            int kc = (v & 3) * 8;
            bf16x8 val = {0, 0, 0, 0, 0, 0, 0, 0};
            int gr = row0 + r;
            if (gr < M)
                val = *(const bf16x8*)(A + (size_t)gr * K + k0 + kc);
            *(bf16x8*)(&As[r][kc]) = val;
        }
        #pragma unroll
        for (int t = 0; t < 2; ++t) {
            int v = tid + t * 256;
            int c = v >> 2;
            int kc = (v & 3) * 8;
            *(bf16x8*)(&Bs[c][kc]) =
                *(const bf16x8*)(BT + (size_t)(col0 + c) * K + k0 + kc);
        }
        __syncthreads();

        bf16x8 ah[2], bh[8];
        #pragma unroll
        for (int m = 0; m < 2; ++m)
            ah[m] = *(const bf16x8*)&As[wv * 32 + m * 16 + l15][kg];
        #pragma unroll
        for (int n = 0; n < 8; ++n)
            bh[n] = *(const bf16x8*)&Bs[n * 16 + l15][kg];
        #pragma unroll
        for (int m = 0; m < 2; ++m)
            #pragma unroll
            for (int n = 0; n < 8; ++n)
                acc[m][n] = __builtin_amdgcn_mfma_f32_16x16x32_bf16(
                    ah[m], bh[n], acc[m][n], 0, 0, 0);
        __syncthreads();
    }

    const int crow = (ln >> 4) * 4;
    #pragma unroll
    for (int m = 0; m < 2; ++m) {
        #pragma unroll
        for (int q = 0; q < 4; ++q) {
            int gr = row0 + wv * 32 + m * 16 + crow + q;
            if (gr >= M) continue;
            if constexpr (EPI == 1) {
                #pragma unroll
                for (int n = 0; n < 8; ++n) {
                    int gc = col0 + n * 16 + l15;
                    float v = acc[m][n][q] + bias[gc];
                    v = fmaxf(v, 0.f);
                    C[(size_t)gr * NN + gc] = f2bf(v);
                }
            } else {
                float sp = 0.f, dp = 0.f;
                #pragma unroll
                for (int n = 0; n < 8; ++n) {
                    int gc = n * 16 + l15;
                    float v = acc[m][n][q];
                    C[(size_t)gr * NN + gc] = f2bf(v);
                    sp += v * va[gc];
                    dp += v * vb[gc];
                }
                #pragma unroll
                for (int off = 1; off < 16; off <<= 1) {
                    sp += __shfl_xor(sp, off);
                    dp += __shfl_xor(dp, off);
                }
                if (l15 == 0) { sOut[gr] = sp; dOut[gr] = dp; }
            }
        }
    }
}

// ---- fused softmax + weighted gather (unchanged) ----
template <bool OUTBF>
__global__ __launch_bounds__(256) void node_gather_k(
    const int* __restrict__ rowptr, const int* __restrict__ ssrc,
    const float* __restrict__ s, const float* __restrict__ d,
    const unsigned short* __restrict__ hsrc, const float* __restrict__ bias,
    unsigned short* __restrict__ obf, float* __restrict__ outf, int N) {
    constexpr int F = 128, G = 8;
    const int node = blockIdx.x * 4 + (threadIdx.x >> 6);
    const int lane = threadIdx.x & 63;
    if (node >= N) return;
    const int beg = rowptr[node];
    const int end = rowptr[node + 1];
    const float dn = d[node];
    const int grp = lane >> 3;
    const int lr = lane & 7;

    float acc[16] = {};
    float zsum = 0.f;
    int j = beg + grp;
    for (; j + G < end; j += 2 * G) {
        int sj0 = ssrc[j];
        int sj1 = ssrc[j + G];
        float e0 = s[sj0] + dn;
        float e1 = s[sj1] + dn;
        const unsigned short* r0 = hsrc + (size_t)sj0 * F + lr * 16;
        const unsigned short* r1 = hsrc + (size_t)sj1 * F + lr * 16;
        bf16x8 v0a = *(const bf16x8*)r0;
        bf16x8 v0b = *(const bf16x8*)(r0 + 8);
        bf16x8 v1a = *(const bf16x8*)r1;
        bf16x8 v1b = *(const bf16x8*)(r1 + 8);
        e0 = (e0 > 0.f) ? e0 : NEG_SLOPE * e0;
        e1 = (e1 > 0.f) ? e1 : NEG_SLOPE * e1;
        float x0 = __expf(e0);
        float x1 = __expf(e1);
        zsum += x0 + x1;
        #pragma unroll
        for (int q = 0; q < 8; ++q) {
            acc[q]     += x0 * bf2f(((unsigned short*)&v0a)[q]);
            acc[q + 8] += x0 * bf2f(((unsigned short*)&v0b)[q]);
            acc[q]     += x1 * bf2f(((unsigned short*)&v1a)[q]);
            acc[q + 8] += x1 * bf2f(((unsigned short*)&v1b)[q]);
        }
    }
    if (j < end) {
        int sj = ssrc[j];
        float e = s[sj] + dn;
        e = (e > 0.f) ? e : NEG_SLOPE * e;
        float exj = __expf(e);
        zsum += exj;
        const unsigned short* r0 = hsrc + (size_t)sj * F + lr * 16;
        bf16x8 va_ = *(const bf16x8*)r0;
        bf16x8 vb_ = *(const bf16x8*)(r0 + 8);
        #pragma unroll
        for (int q = 0; q < 8; ++q) {
            acc[q]     += exj * bf2f(((unsigned short*)&va_)[q]);
            acc[q + 8] += exj * bf2f(((unsigned short*)&vb_)[q]);
        }
    }
    #pragma unroll
    for (int off = 8; off < 64; off <<= 1) {
        zsum += __shfl_xor(zsum, off);
        #pragma unroll
        for (int q = 0; q < 16; ++q) acc[q] += __shfl_xor(acc[q], off);
    }
    const float inv = 1.f / zsum;

    if (lane < 8) {
        if constexpr (OUTBF) {
            bf16x8 w0, w1;
            #pragma unroll
            for (int q = 0; q < 8; ++q) {
                ((unsigned short*)&w0)[q] = f2bf(acc[q] * inv);
                ((unsigned short*)&w1)[q] = f2bf(acc[q + 8] * inv);
            }
            *(bf16x8*)(obf + (size_t)node * F + lr * 16) = w0;
            *(bf16x8*)(obf + (size_t)node * F + lr * 16 + 8) = w1;
        } else {
            float o[16];
            #pragma unroll
            for (int q = 0; q < 16; ++q)
                o[q] = acc[q] * inv + bias[lr * 16 + q];
            float* op = outf + (size_t)node * F + lr * 16;
            *(float4*)op = {o[0], o[1], o[2], o[3]};
            *(float4*)(op + 4) = {o[4], o[5], o[6], o[7]};
            *(float4*)(op + 8) = {o[8], o[9], o[10], o[11]};
            *(float4*)(op + 12) = {o[12], o[13], o[14], o[15]};
        }
    }
}

extern "C" void kernel_launch(void* const* d_in, const int* in_sizes, int n_in,
                              void* d_out, int out_size, void* d_ws, size_t ws_size,
                              hipStream_t stream) {
    const float* x      = (const float*)d_in[0];
    const int*   eidx   = (const int*)d_in[1];
    const float* W1     = (const float*)d_in[2];
    const float* a_src1 = (const float*)d_in[3];
    const float* a_dst1 = (const float*)d_in[4];
    const float* b1     = (const float*)d_in[5];
    const float* W2     = (const float*)d_in[6];
    const float* a_src2 = (const float*)d_in[7];
    const float* a_dst2 = (const float*)d_in[8];
    const float* b2     = (const float*)d_in[9];

    const int N = in_sizes[0] / 128;   // 50000
    const int E = in_sizes[1] / 2;     // 800000
    const int F_IN = 128, H = 256, F_OUT = 128;
    const int EA = E + N;

    const int* srcE = eidx;
    const int* dstE = eidx + E;

    // ---- workspace layout ----
    unsigned short* xbf    = (unsigned short*)d_ws;                 // N*128 bf16
    unsigned short* aggx   = xbf + (size_t)N * F_IN;                // N*128 bf16
    unsigned short* g1     = aggx + (size_t)N * F_IN;               // N*256 bf16
    unsigned short* h2bf   = g1 + (size_t)N * H;                    // N*128 bf16
    float*          sbuf   = (float*)(h2bf + (size_t)N * F_OUT);    // N
    float*          dbuf   = sbuf + N;                              // N
    float*          w_s1   = dbuf + N;                              // 128
    float*          w_d1   = w_s1 + F_IN;                           // 128
    unsigned short* w1T    = (unsigned short*)(w_d1 + F_IN);        // 256*128
    unsigned short* w2T    = w1T + 32768;                           // 128*256
    int*            rowptr = (int*)(w2T + 32768);                   // N+1
    int*            histG  = rowptr + (N + 1);                      // NB*NBUCKET
    int*            colSum = histG + NB * NBUCKET;                  // NBUCKET
    int*            ssrc   = colSum + NBUCKET;                      // E+N
    unsigned*       packed = (unsigned*)(ssrc + EA);                // E+N

    float* out = (float*)d_out;
    const int xblocks = (N * 64 + 255) / 256;   // 12500

    // 1) bucket histograms + weight prep
    hist_wprep_k<<<NB + 288, 256, 0, stream>>>(
        dstE, W1, W2, a_src1, a_dst1, histG, w1T, w2T, w_s1, w_d1, E, N);
    // 2) column scan + xprep
    colscan_xprep_k<<<NBUCKET / 4 + xblocks, 256, 0, stream>>>(
        histG, colSum, x, w_s1, w_d1, xbf, sbuf, dbuf, N);
    // 3) scatter into bucket-grouped order (bb scanned in LDS)
    bscatter_k<<<NB, 256, 0, stream>>>(srcE, dstE, histG, colSum, packed, E, N);
    // 4) per-bucket counting sort -> ssrc + rowptr
    bsort_k<<<NBUCKET, 256, 0, stream>>>(packed, colSum, ssrc, rowptr, EA, N);

    // 5) layer-1 gather
    {
        int nb = (N + 3) / 4;
        node_gather_k<true><<<nb, 256, 0, stream>>>(
            rowptr, ssrc, sbuf, dbuf, xbf, nullptr, aggx, nullptr, N);
    }
    // 6) GEMM1 (relu+bias epilogue)
    {
        dim3 gg((N + 127) / 128, H / 128);
        gemm_bf16<128, 256, 1><<<gg, 256, 0, stream>>>(
            aggx, w1T, g1, b1, nullptr, nullptr, nullptr, nullptr, N);
    }
    // 7) GEMM2 (+ in-epilogue layer-2 rowdots)
    {
        dim3 gg((N + 127) / 128, 1);
        gemm_bf16<256, 128, 2><<<gg, 256, 0, stream>>>(
            g1, w2T, h2bf, nullptr, a_src2, a_dst2, sbuf, dbuf, N);
    }
    // 8) layer-2 gather (final output)
    {
        int nb = (N + 3) / 4;
        node_gather_k<false><<<nb, 256, 0, stream>>>(
            rowptr, ssrc, sbuf, dbuf, h2bf, b2, nullptr, out, N);
    }
}

// Round 19
// 145.635 us; speedup vs baseline: 3.8621x; 1.0569x over previous
//
#include <hip/hip_runtime.h>
#include <hip/hip_bf16.h>

// ---------------------------------------------------------------------------
// GAT encoder, 2 layers. Round 19: round-18 pipeline, CSR occupancy fix:
// NB 104->416 (EPB 8192->2048) so hist/bscatter use the whole 256-CU chip
// (104 blocks left >half the machine idle). colscan loop widened to 7 waves.
// 8 dispatches: K1 hist+wprep | K2 colscan+xprep | K3 bscatter | K4 bsort |
// gather1 | gemm1 | gemm2 | gather2.
// ---------------------------------------------------------------------------

#define NEG_SLOPE 0.2f
#define NB 416          // hist/scatter blocks (>= CU count)
#define EPB 2048        // edges per block; NB*EPB = 851968 >= E+N
#define NBUCKET 1568    // buckets of 32 dsts
#define BSH 5

typedef __attribute__((ext_vector_type(8))) short bf16x8;
typedef __attribute__((ext_vector_type(4))) float f32x4;

__device__ __forceinline__ unsigned short f2bf(float v) {
    __hip_bfloat16 b = __float2bfloat16(v);
    return *reinterpret_cast<unsigned short*>(&b);
}
__device__ __forceinline__ float bf2f(unsigned short u) {
    __hip_bfloat16 b = *reinterpret_cast<__hip_bfloat16*>(&u);
    return __bfloat162float(b);
}

// ---- K1: blocks [0,NB): LDS bucket histogram. [NB,NB+256): W transposes.
//      [NB+256,NB+288): W1 projection dots. ----
__global__ __launch_bounds__(256) void hist_wprep_k(
    const int* __restrict__ dstE, const float* __restrict__ W1,
    const float* __restrict__ W2, const float* __restrict__ a_src1,
    const float* __restrict__ a_dst1, int* __restrict__ histG,
    unsigned short* __restrict__ w1T, unsigned short* __restrict__ w2T,
    float* __restrict__ w_s1, float* __restrict__ w_d1, int E, int N) {
    const int b = blockIdx.x;
    if (b < NB) {
        __shared__ int h[NBUCKET];
        for (int i = threadIdx.x; i < NBUCKET; i += 256) h[i] = 0;
        __syncthreads();
        const int base = b * EPB;
        const int total = E + N;
        #pragma unroll
        for (int q = 0; q < EPB / 256; ++q) {
            int i = base + q * 256 + threadIdx.x;
            if (i < total) {
                int di = (i < E) ? dstE[i] : i - E;
                atomicAdd(&h[di >> BSH], 1);
            }
        }
        __syncthreads();
        for (int i = threadIdx.x; i < NBUCKET; i += 256)
            histG[b * NBUCKET + i] = h[i];
    } else if (b < NB + 128) {           // W1[128][256] -> w1T[256][128]
        int i = (b - NB) * 256 + threadIdx.x;
        int k = i >> 8, n = i & 255;
        w1T[n * 128 + k] = f2bf(W1[i]);
    } else if (b < NB + 256) {           // W2[256][128] -> w2T[128][256]
        int j = (b - NB - 128) * 256 + threadIdx.x;
        int k = j >> 7, n = j & 127;
        w2T[n * 256 + k] = f2bf(W2[j]);
    } else {                             // projection dots
        int w = ((b - NB - 256) * 256 + threadIdx.x) >> 6;  // 0..127
        int lane = threadIdx.x & 63;
        const float* row = W1 + (size_t)w * 256;
        float ss = 0.f, dd = 0.f;
        #pragma unroll
        for (int f = lane; f < 256; f += 64) {
            float v = row[f];
            ss += v * a_src1[f];
            dd += v * a_dst1[f];
        }
        #pragma unroll
        for (int off = 32; off; off >>= 1) {
            ss += __shfl_down(ss, off);
            dd += __shfl_down(dd, off);
        }
        if (lane == 0) { w_s1[w] = ss; w_d1[w] = dd; }
    }
}

// ---- K2: blocks [0, NBUCKET/4): per-bucket column scan (histG in place,
//      colSum out). blocks after: xprep (x->bf16 + s/d dots). ----
__global__ __launch_bounds__(256) void colscan_xprep_k(
    int* __restrict__ histG, int* __restrict__ colSum,
    const float* __restrict__ x, const float* __restrict__ va,
    const float* __restrict__ vb, unsigned short* __restrict__ xbf,
    float* __restrict__ s, float* __restrict__ d, int N) {
    const int b = blockIdx.x;
    constexpr int CSB = NBUCKET / 4;   // 392
    if (b < CSB) {
        const int bkt = b * 4 + (threadIdx.x >> 6);
        const int l = threadIdx.x & 63;
        int carry = 0;
        #pragma unroll
        for (int c = 0; c < (NB + 63) / 64; ++c) {
            int blk = c * 64 + l;
            int v = (blk < NB) ? histG[blk * NBUCKET + bkt] : 0;
            int incl = v;
            #pragma unroll
            for (int off = 1; off < 64; off <<= 1) {
                int t = __shfl_up(incl, off);
                if (l >= off) incl += t;
            }
            if (blk < NB) histG[blk * NBUCKET + bkt] = carry + (incl - v);
            carry += __shfl(incl, 63);
        }
        if (l == 0) colSum[bkt] = carry;
    } else {
        int w = (((b - CSB) * 256) + threadIdx.x) >> 6;
        int lane = threadIdx.x & 63;
        if (w >= N) return;
        float2 v = *(const float2*)(x + (size_t)w * 128 + lane * 2);
        ushort2 u;
        u.x = f2bf(v.x);
        u.y = f2bf(v.y);
        *(ushort2*)(xbf + (size_t)w * 128 + lane * 2) = u;
        float ss = v.x * va[lane * 2] + v.y * va[lane * 2 + 1];
        float dd = v.x * vb[lane * 2] + v.y * vb[lane * 2 + 1];
        #pragma unroll
        for (int off = 32; off; off >>= 1) {
            ss += __shfl_down(ss, off);
            dd += __shfl_down(dd, off);
        }
        if (lane == 0) { s[w] = ss; d[w] = dd; }
    }
}

// ---- K3: scatter packed (dst<<16|src) into bucket-grouped order.
//      Bucket bases computed in-LDS (exclusive scan of colSum). ----
__global__ __launch_bounds__(256) void bscatter_k(
    const int* __restrict__ srcE, const int* __restrict__ dstE,
    const int* __restrict__ histG, const int* __restrict__ colSum,
    unsigned* __restrict__ packed, int E, int N) {
    __shared__ int bb_s[NBUCKET];
    __shared__ int cur[NBUCKET];
    __shared__ int wsum[4];
    const int tid = threadIdx.x;
    // exclusive scan of colSum -> bb_s
    {
        const int lane = tid & 63, wv = tid >> 6;
        const int base = tid * 7;   // 256*7 >= NBUCKET
        int loc[7];
        int ssum = 0;
        #pragma unroll
        for (int q = 0; q < 7; ++q) {
            int idx = base + q;
            int c = (idx < NBUCKET) ? colSum[idx] : 0;
            loc[q] = ssum;
            ssum += c;
        }
        int incl = ssum;
        #pragma unroll
        for (int off = 1; off < 64; off <<= 1) {
            int t = __shfl_up(incl, off);
            if (lane >= off) incl += t;
        }
        if (lane == 63) wsum[wv] = incl;
        __syncthreads();
        if (tid == 0) {
            int r = 0;
            #pragma unroll
            for (int i = 0; i < 4; ++i) { int c = wsum[i]; wsum[i] = r; r += c; }
        }
        __syncthreads();
        const int b0 = wsum[wv] + (incl - ssum);
        #pragma unroll
        for (int q = 0; q < 7; ++q) {
            int idx = base + q;
            if (idx < NBUCKET) bb_s[idx] = b0 + loc[q];
        }
    }
    for (int i = tid; i < NBUCKET; i += 256) cur[i] = 0;
    __syncthreads();
    const int b = blockIdx.x;
    const int base = b * EPB;
    const int total = E + N;
    #pragma unroll
    for (int q = 0; q < EPB / 256; ++q) {
        int i = base + q * 256 + tid;
        if (i < total) {
            int di, si;
            if (i < E) { di = dstE[i]; si = srcE[i]; }
            else       { di = si = i - E; }
            int bk = di >> BSH;
            int r = atomicAdd(&cur[bk], 1);
            packed[bb_s[bk] + histG[b * NBUCKET + bk] + r] =
                ((unsigned)di << 16) | (unsigned)si;
        }
    }
}

// ---- K4: per-bucket LDS counting sort; beg via block reduce of colSum. ----
__global__ __launch_bounds__(256) void bsort_k(
    const unsigned* __restrict__ packed, const int* __restrict__ colSum,
    int* __restrict__ ssrc, int* __restrict__ rowptr, int EA, int N) {
    __shared__ unsigned arr[2048];
    __shared__ int cnt[32], pf[32], cur[32];
    __shared__ int red[4];
    __shared__ int beg_s;
    const int b = blockIdx.x;
    const int tid = threadIdx.x;
    // beg = sum(colSum[0..b))
    {
        int part = 0;
        for (int i = tid; i < b; i += 256) part += colSum[i];
        #pragma unroll
        for (int off = 32; off; off >>= 1) part += __shfl_down(part, off);
        if ((tid & 63) == 0) red[tid >> 6] = part;
        __syncthreads();
        if (tid == 0) beg_s = red[0] + red[1] + red[2] + red[3];
    }
    if (tid < 32) cnt[tid] = 0;
    __syncthreads();
    const int beg = beg_s;
    const int L = colSum[b];
    for (int t = tid; t < L; t += 256) {
        unsigned e = packed[beg + t];
        arr[t] = e;
        atomicAdd(&cnt[(e >> 16) & 31], 1);
    }
    __syncthreads();
    if (tid == 0) {
        int r = 0;
        #pragma unroll
        for (int j = 0; j < 32; ++j) { pf[j] = r; cur[j] = r; r += cnt[j]; }
    }
    __syncthreads();
    if (tid < 32) {
        int dd = b * 32 + tid;
        if (dd < N) rowptr[dd] = beg + pf[tid];
    }
    for (int t = tid; t < L; t += 256) {
        unsigned e = arr[t];
        int r = atomicAdd(&cur[(e >> 16) & 31], 1);
        ssrc[beg + r] = (int)(e & 0xffffu);
    }
    if (b == 0 && tid == 0) rowptr[N] = EA;
}

// ---- bf16 MFMA GEMM, BM=128 BN=128 BK=32 (unchanged) ----
template <int K, int NN, int EPI>
__global__ __launch_bounds__(256) void gemm_bf16(
    const unsigned short* __restrict__ A, const unsigned short* __restrict__ BT,
    unsigned short* __restrict__ C, const float* __restrict__ bias,
    const float* __restrict__ va, const float* __restrict__ vb,
    float* __restrict__ sOut, float* __restrict__ dOut, int M) {
    constexpr int BK = 32, PAD = 8;
    __shared__ short As[128][BK + PAD];
    __shared__ short Bs[128][BK + PAD];
    const int tid = threadIdx.x;
    const int wv = tid >> 6;
    const int ln = tid & 63;
    const int row0 = blockIdx.x * 128;
    const int col0 = blockIdx.y * 128;

    f32x4 acc[2][8];
    #pragma unroll
    for (int m = 0; m < 2; ++m)
        #pragma unroll
        for (int n = 0; n < 8; ++n) acc[m][n] = {0.f, 0.f, 0.f, 0.f};

    const int l15 = ln & 15;
    const int kg = (ln >> 4) * 8;

    for (int k0 = 0; k0 < K; k0 += BK) {
        #pragma unroll
        for (int t = 0; t < 2; ++t) {
            int v = tid + t * 256;
            int r = v >> 2;
            int kc = (v & 3) * 8;
            bf16x8 val = {0, 0, 0, 0, 0, 0, 0, 0};
            int gr = row0 + r;
            if (gr < M)
                val = *(const bf16x8*)(A + (size_t)gr * K + k0 + kc);
            *(bf16x8*)(&As[r][kc]) = val;
        }
        #pragma unroll
        for (int t = 0; t < 2; ++t) {
            int v = tid + t * 256;
            int c = v >> 2;
            int kc = (v & 3) * 8;
            *(bf16x8*)(&Bs[c][kc]) =
                *(const bf16x8*)(BT + (size_t)(col0 + c) * K + k0 + kc);
        }
        __syncthreads();

        bf16x8 ah[2], bh[8];
        #pragma unroll
        for (int m = 0; m < 2; ++m)
            ah[m] = *(const bf16x8*)&As[wv * 32 + m * 16 + l15][kg];
        #pragma unroll
        for (int n = 0; n < 8; ++n)
            bh[n] = *(const bf16x8*)&Bs[n * 16 + l15][kg];
        #pragma unroll
        for (int m = 0; m < 2; ++m)
            #pragma unroll
            for (int n = 0; n < 8; ++n)
                acc[m][n] = __builtin_amdgcn_mfma_f32_16x16x32_bf16(
                    ah[m], bh[n], acc[m][n], 0, 0, 0);
        __syncthreads();
    }

    const int crow = (ln >> 4) * 4;
    #pragma unroll
    for (int m = 0; m < 2; ++m) {
        #pragma unroll
        for (int q = 0; q < 4; ++q) {
            int gr = row0 + wv * 32 + m * 16 + crow + q;
            if (gr >= M) continue;
            if constexpr (EPI == 1) {
                #pragma unroll
                for (int n = 0; n < 8; ++n) {
                    int gc = col0 + n * 16 + l15;
                    float v = acc[m][n][q] + bias[gc];
                    v = fmaxf(v, 0.f);
                    C[(size_t)gr * NN + gc] = f2bf(v);
                }
            } else {
                float sp = 0.f, dp = 0.f;
                #pragma unroll
                for (int n = 0; n < 8; ++n) {
                    int gc = n * 16 + l15;
                    float v = acc[m][n][q];
                    C[(size_t)gr * NN + gc] = f2bf(v);
                    sp += v * va[gc];
                    dp += v * vb[gc];
                }
                #pragma unroll
                for (int off = 1; off < 16; off <<= 1) {
                    sp += __shfl_xor(sp, off);
                    dp += __shfl_xor(dp, off);
                }
                if (l15 == 0) { sOut[gr] = sp; dOut[gr] = dp; }
            }
        }
    }
}

// ---- fused softmax + weighted gather (unchanged) ----
template <bool OUTBF>
__global__ __launch_bounds__(256) void node_gather_k(
    const int* __restrict__ rowptr, const int* __restrict__ ssrc,
    const float* __restrict__ s, const float* __restrict__ d,
    const unsigned short* __restrict__ hsrc, const float* __restrict__ bias,
    unsigned short* __restrict__ obf, float* __restrict__ outf, int N) {
    constexpr int F = 128, G = 8;
    const int node = blockIdx.x * 4 + (threadIdx.x >> 6);
    const int lane = threadIdx.x & 63;
    if (node >= N) return;
    const int beg = rowptr[node];
    const int end = rowptr[node + 1];
    const float dn = d[node];
    const int grp = lane >> 3;
    const int lr = lane & 7;

    float acc[16] = {};
    float zsum = 0.f;
    int j = beg + grp;
    for (; j + G < end; j += 2 * G) {
        int sj0 = ssrc[j];
        int sj1 = ssrc[j + G];
        float e0 = s[sj0] + dn;
        float e1 = s[sj1] + dn;
        const unsigned short* r0 = hsrc + (size_t)sj0 * F + lr * 16;
        const unsigned short* r1 = hsrc + (size_t)sj1 * F + lr * 16;
        bf16x8 v0a = *(const bf16x8*)r0;
        bf16x8 v0b = *(const bf16x8*)(r0 + 8);
        bf16x8 v1a = *(const bf16x8*)r1;
        bf16x8 v1b = *(const bf16x8*)(r1 + 8);
        e0 = (e0 > 0.f) ? e0 : NEG_SLOPE * e0;
        e1 = (e1 > 0.f) ? e1 : NEG_SLOPE * e1;
        float x0 = __expf(e0);
        float x1 = __expf(e1);
        zsum += x0 + x1;
        #pragma unroll
        for (int q = 0; q < 8; ++q) {
            acc[q]     += x0 * bf2f(((unsigned short*)&v0a)[q]);
            acc[q + 8] += x0 * bf2f(((unsigned short*)&v0b)[q]);
            acc[q]     += x1 * bf2f(((unsigned short*)&v1a)[q]);
            acc[q + 8] += x1 * bf2f(((unsigned short*)&v1b)[q]);
        }
    }
    if (j < end) {
        int sj = ssrc[j];
        float e = s[sj] + dn;
        e = (e > 0.f) ? e : NEG_SLOPE * e;
        float exj = __expf(e);
        zsum += exj;
        const unsigned short* r0 = hsrc + (size_t)sj * F + lr * 16;
        bf16x8 va_ = *(const bf16x8*)r0;
        bf16x8 vb_ = *(const bf16x8*)(r0 + 8);
        #pragma unroll
        for (int q = 0; q < 8; ++q) {
            acc[q]     += exj * bf2f(((unsigned short*)&va_)[q]);
            acc[q + 8] += exj * bf2f(((unsigned short*)&vb_)[q]);
        }
    }
    #pragma unroll
    for (int off = 8; off < 64; off <<= 1) {
        zsum += __shfl_xor(zsum, off);
        #pragma unroll
        for (int q = 0; q < 16; ++q) acc[q] += __shfl_xor(acc[q], off);
    }
    const float inv = 1.f / zsum;

    if (lane < 8) {
        if constexpr (OUTBF) {
            bf16x8 w0, w1;
            #pragma unroll
            for (int q = 0; q < 8; ++q) {
                ((unsigned short*)&w0)[q] = f2bf(acc[q] * inv);
                ((unsigned short*)&w1)[q] = f2bf(acc[q + 8] * inv);
            }
            *(bf16x8*)(obf + (size_t)node * F + lr * 16) = w0;
            *(bf16x8*)(obf + (size_t)node * F + lr * 16 + 8) = w1;
        } else {
            float o[16];
            #pragma unroll
            for (int q = 0; q < 16; ++q)
                o[q] = acc[q] * inv + bias[lr * 16 + q];
            float* op = outf + (size_t)node * F + lr * 16;
            *(float4*)op = {o[0], o[1], o[2], o[3]};
            *(float4*)(op + 4) = {o[4], o[5], o[6], o[7]};
            *(float4*)(op + 8) = {o[8], o[9], o[10], o[11]};
            *(float4*)(op + 12) = {o[12], o[13], o[14], o[15]};
        }
    }
}

extern "C" void kernel_launch(void* const* d_in, const int* in_sizes, int n_in,
                              void* d_out, int out_size, void* d_ws, size_t ws_size,
                              hipStream_t stream) {
    const float* x      = (const float*)d_in[0];
    const int*   eidx   = (const int*)d_in[1];
    const float* W1     = (const float*)d_in[2];
    const float* a_src1 = (const float*)d_in[3];
    const float* a_dst1 = (const float*)d_in[4];
    const float* b1     = (const float*)d_in[5];
    const float* W2     = (const float*)d_in[6];
    const float* a_src2 = (const float*)d_in[7];
    const float* a_dst2 = (const float*)d_in[8];
    const float* b2     = (const float*)d_in[9];

    const int N = in_sizes[0] / 128;   // 50000
    const int E = in_sizes[1] / 2;     // 800000
    const int F_IN = 128, H = 256, F_OUT = 128;
    const int EA = E + N;

    const int* srcE = eidx;
    const int* dstE = eidx + E;

    // ---- workspace layout ----
    unsigned short* xbf    = (unsigned short*)d_ws;                 // N*128 bf16
    unsigned short* aggx   = xbf + (size_t)N * F_IN;                // N*128 bf16
    unsigned short* g1     = aggx + (size_t)N * F_IN;               // N*256 bf16
    unsigned short* h2bf   = g1 + (size_t)N * H;                    // N*128 bf16
    float*          sbuf   = (float*)(h2bf + (size_t)N * F_OUT);    // N
    float*          dbuf   = sbuf + N;                              // N
    float*          w_s1   = dbuf + N;                              // 128
    float*          w_d1   = w_s1 + F_IN;                           // 128
    unsigned short* w1T    = (unsigned short*)(w_d1 + F_IN);        // 256*128
    unsigned short* w2T    = w1T + 32768;                           // 128*256
    int*            rowptr = (int*)(w2T + 32768);                   // N+1
    int*            histG  = rowptr + (N + 1);                      // NB*NBUCKET
    int*            colSum = histG + NB * NBUCKET;                  // NBUCKET
    int*            ssrc   = colSum + NBUCKET;                      // E+N
    unsigned*       packed = (unsigned*)(ssrc + EA);                // E+N

    float* out = (float*)d_out;
    const int xblocks = (N * 64 + 255) / 256;   // 12500

    // 1) bucket histograms + weight prep
    hist_wprep_k<<<NB + 288, 256, 0, stream>>>(
        dstE, W1, W2, a_src1, a_dst1, histG, w1T, w2T, w_s1, w_d1, E, N);
    // 2) column scan + xprep
    colscan_xprep_k<<<NBUCKET / 4 + xblocks, 256, 0, stream>>>(
        histG, colSum, x, w_s1, w_d1, xbf, sbuf, dbuf, N);
    // 3) scatter into bucket-grouped order (bb scanned in LDS)
    bscatter_k<<<NB, 256, 0, stream>>>(srcE, dstE, histG, colSum, packed, E, N);
    // 4) per-bucket counting sort -> ssrc + rowptr
    bsort_k<<<NBUCKET, 256, 0, stream>>>(packed, colSum, ssrc, rowptr, EA, N);

    // 5) layer-1 gather
    {
        int nb = (N + 3) / 4;
        node_gather_k<true><<<nb, 256, 0, stream>>>(
            rowptr, ssrc, sbuf, dbuf, xbf, nullptr, aggx, nullptr, N);
    }
    // 6) GEMM1 (relu+bias epilogue)
    {
        dim3 gg((N + 127) / 128, H / 128);
        gemm_bf16<128, 256, 1><<<gg, 256, 0, stream>>>(
            aggx, w1T, g1, b1, nullptr, nullptr, nullptr, nullptr, N);
    }
    // 7) GEMM2 (+ in-epilogue layer-2 rowdots)
    {
        dim3 gg((N + 127) / 128, 1);
        gemm_bf16<256, 128, 2><<<gg, 256, 0, stream>>>(
            g1, w2T, h2bf, nullptr, a_src2, a_dst2, sbuf, dbuf, N);
    }
    // 8) layer-2 gather (final output)
    {
        int nb = (N + 3) / 4;
        node_gather_k<false><<<nb, 256, 0, stream>>>(
            rowptr, ssrc, sbuf, dbuf, h2bf, b2, nullptr, out, N);
    }
}